// Round 5
// baseline (472.104 us; speedup 1.0000x reference)
//
#include <hip/hip_runtime.h>
#include <math.h>

// Problem constants (fixed by reference): B=64, N=512, D=64, H=4, C=64, L=3
// Workspace layout (floats):
//   xbuf [0 .. 2097152)        : layer activations x (B*N*64) = 8 MB
//     -- prep metadata (3 MB) overlaid at FRONT of xbuf between lin (reads x)
//        and finalize (rewrites x); stream order makes it safe.
//   hbuf [2097152 .. 10485760) : h (B*N*H*C) = 32 MB; yH aliases h.

// ---------------------------------------------------------------------------
// Kernel A v3: h[gn][o] = sum_d x[gn][d] * W[o][d]
// No LDS. Thread owns row gn: x[gn][0:64] in 16 float4 VGPRs; W indices are
// wave-uniform -> s_load/SGPR broadcast (scalar pipe), v_fma with 1 SGPR src.
// Block = 256 thr (one row each), grid = (128 row-groups, 4 o-quarters).
// 4096 FMA/thread = 8192 issue cyc; VALU floor ~6.8 us/dispatch.
// (R1-R4 history: 128x128 LDS tile was latency-bound at 45 us, VALUBusy 13%.)
// ---------------------------------------------------------------------------
__global__ __launch_bounds__(256) void lin_kernel(const float* __restrict__ x,
                                                  const float* __restrict__ W,
                                                  float* __restrict__ h) {
    const int t = threadIdx.x;
    const int gn = blockIdx.x * 256 + t;
    const int o0 = blockIdx.y * 64;

    // x row -> registers (64 VGPRs)
    float4 xr[16];
    const float4* xp = (const float4*)(x + (size_t)gn * 64);
#pragma unroll
    for (int i = 0; i < 16; ++i) xr[i] = xp[i];

    float acc[64];
#pragma unroll
    for (int j = 0; j < 64; ++j) acc[j] = 0.f;

#pragma unroll 1
    for (int jc = 0; jc < 8; ++jc) {           // 8 chunks of 8 outputs
        const float* Wc = W + (size_t)(o0 + jc * 8) * 64;   // wave-uniform
#pragma unroll
        for (int d4 = 0; d4 < 16; ++d4) {
            float4 xv = xr[d4];
#pragma unroll
            for (int j = 0; j < 8; ++j) {
                float4 w = *(const float4*)(Wc + j * 64 + d4 * 4);  // -> s_load
                acc[jc * 8 + j] += w.x * xv.x + w.y * xv.y + w.z * xv.z + w.w * xv.w;
            }
        }
    }

    float* hp = h + (size_t)gn * 256 + o0;
#pragma unroll
    for (int q = 0; q < 16; ++q)
        *(float4*)(hp + q * 4) = make_float4(acc[q * 4], acc[q * 4 + 1],
                                             acc[q * 4 + 2], acc[q * 4 + 3]);
}

// ---------------------------------------------------------------------------
// Kernel B1: attn_prep v2 — per (b,head). Shuffle-based bitonic sort (2
// consecutive elements/thread: j=1 in-reg, j<=64 shfl_xor, j in {128,256} via
// LDS -> only 3 barrier-stages vs 45). Wave-shfl scans for z1suf/z2pre.
// ---------------------------------------------------------------------------
__global__ __launch_bounds__(256) void attn_prep(const float* __restrict__ h,
                                                 const float* __restrict__ att_src,
                                                 const float* __restrict__ att_dst,
                                                 int* __restrict__ g_sidx,
                                                 float* __restrict__ g_E1,
                                                 float* __restrict__ g_E2,
                                                 float* __restrict__ g_aZ,
                                                 float* __restrict__ g_bZ,
                                                 int* __restrict__ g_k) {
    const int bh = blockIdx.x;
    const int b = bh >> 2;
    const int head = bh & 3;
    const int t = threadIdx.x;
    const int lane = t & 63;
    const int wid = t >> 6;

    __shared__ float att_s[64], att_d[64];
    __shared__ float s_val[512];
    __shared__ int   s_idxE[512];
    __shared__ float dArr[512];
    __shared__ float z1suf[513], z2pre[513];
    __shared__ float wred[8];

    if (t < 64) att_s[t] = att_src[head * 64 + t];
    else if (t < 128) att_d[t - 64] = att_dst[head * 64 + (t - 64)];
    __syncthreads();

    for (int rr = 0; rr < 2; ++rr) {
        int j = t + rr * 256;
        const float* hrow = h + ((size_t)(b * 512 + j) * 4 + head) * 64;
        float as = 0.f, ad = 0.f;
#pragma unroll
        for (int d4 = 0; d4 < 16; ++d4) {
            float4 hv = *(const float4*)(hrow + d4 * 4);
            float4 sv = *(const float4*)(att_s + d4 * 4);
            float4 dv = *(const float4*)(att_d + d4 * 4);
            as += hv.x * sv.x + hv.y * sv.y + hv.z * sv.z + hv.w * sv.w;
            ad += hv.x * dv.x + hv.y * dv.y + hv.z * dv.z + hv.w * dv.w;
        }
        s_val[j] = as; dArr[j] = ad;
    }
    __syncthreads();

    // Bitonic sort ascending; thread t holds positions 2t, 2t+1.
    float v0 = s_val[2 * t], v1 = s_val[2 * t + 1];
    int id0 = 2 * t, id1 = 2 * t + 1;
    for (int k = 2; k <= 512; k <<= 1) {
        for (int j = k >> 1; j >= 1; j >>= 1) {
            bool asc = ((t & (k >> 1)) == 0);
            if (j == 1) {
                bool sw = asc ? (v0 > v1) : (v0 < v1);
                if (sw) { float tv = v0; v0 = v1; v1 = tv; int ti = id0; id0 = id1; id1 = ti; }
            } else if (j <= 64) {
                int m = j >> 1;
                float w0 = __shfl_xor(v0, m, 64);
                int  wi0 = __shfl_xor(id0, m, 64);
                float w1 = __shfl_xor(v1, m, 64);
                int  wi1 = __shfl_xor(id1, m, 64);
                bool low = ((t & m) == 0);
                bool wantmin = (low == asc);
                if (wantmin ? (w0 < v0) : (w0 > v0)) { v0 = w0; id0 = wi0; }
                if (wantmin ? (w1 < v1) : (w1 > v1)) { v1 = w1; id1 = wi1; }
            } else {
                int m = j >> 1;
                s_val[2 * t] = v0; s_val[2 * t + 1] = v1;
                s_idxE[2 * t] = id0; s_idxE[2 * t + 1] = id1;
                __syncthreads();
                int tp = t ^ m;
                float w0 = s_val[2 * tp], w1 = s_val[2 * tp + 1];
                int wi0 = s_idxE[2 * tp], wi1 = s_idxE[2 * tp + 1];
                bool low = ((t & m) == 0);
                bool wantmin = (low == asc);
                if (wantmin ? (w0 < v0) : (w0 > v0)) { v0 = w0; id0 = wi0; }
                if (wantmin ? (w1 < v1) : (w1 > v1)) { v1 = w1; id1 = wi1; }
                __syncthreads();
            }
        }
    }

    s_val[2 * t] = v0; s_val[2 * t + 1] = v1;
    __syncthreads();
    const float M = s_val[511];
    float e1_0 = __expf(v0 - M), e1_1 = __expf(v1 - M);
    float e2_0 = __expf(0.2f * (v0 - M)), e2_1 = __expf(0.2f * (v1 - M));
    *(float2*)(g_E1 + bh * 512 + 2 * t) = make_float2(e1_0, e1_1);
    *(float2*)(g_E2 + bh * 512 + 2 * t) = make_float2(e2_0, e2_1);
    *(int2*)(g_sidx + bh * 512 + 2 * t) = make_int2(id0, id1);

    float S1 = e1_0 + e1_1, S2 = e2_0 + e2_1;
    float i1 = S1, i2 = S2;
    for (int off = 1; off < 64; off <<= 1) {
        float u1 = __shfl_up(i1, off, 64);
        float u2 = __shfl_up(i2, off, 64);
        if (lane >= off) { i1 += u1; i2 += u2; }
    }
    if (lane == 63) { wred[wid] = i1; wred[4 + wid] = i2; }
    __syncthreads();
    float off1 = 0.f, off2 = 0.f;
    for (int w = 0; w < wid; ++w) { off1 += wred[w]; off2 += wred[4 + w]; }
    const float T1 = wred[0] + wred[1] + wred[2] + wred[3];
    const float T2 = wred[4] + wred[5] + wred[6] + wred[7];
    float pre1 = off1 + i1 - S1;
    float pre2 = off2 + i2 - S2;
    z1suf[2 * t] = T1 - pre1;
    z1suf[2 * t + 1] = T1 - pre1 - e1_0;
    z2pre[2 * t] = pre2;
    z2pre[2 * t + 1] = pre2 + e2_0;
    if (t == 0) { z1suf[512] = 0.f; z2pre[512] = T2; }
    __syncthreads();

    for (int rr = 0; rr < 2; ++rr) {
        int i = t + rr * 256;
        float d = dArr[i];
        int lo = 0, hi = 512;
        while (lo < hi) {
            int mid = (lo + hi) >> 1;
            if (d + s_val[mid] >= 0.f) hi = mid; else lo = mid + 1;
        }
        int k = lo;
        float g = d + M;
        float G = (g >= 0.f) ? g : 0.2f * g;
        float al = __expf(g - G);
        float be = __expf(0.2f * g - G);
        float Z = al * z1suf[k] + be * z2pre[k];
        float inv = 1.0f / Z;
        g_aZ[bh * 512 + i] = al * inv;
        g_bZ[bh * 512 + i] = be * inv;
        g_k[bh * 512 + i]  = k;
    }
}

// ---------------------------------------------------------------------------
// Kernel B2: attn_agg v2 — 16 channels/block (grid 1024). 64-B aligned h
// gather held in registers; ONE 33-KB LDS table used twice. XCD swizzle:
// blockIdx = q*64 + b so all 16 blocks of a batch share an XCD.
// yH aliases h: all h reads (phase 0) precede yH writes (end), block-local.
// ---------------------------------------------------------------------------
#define APW 516
__global__ __launch_bounds__(256) void attn_agg(const float* __restrict__ h,
                                                const int* __restrict__ g_sidx,
                                                const float* __restrict__ g_E1,
                                                const float* __restrict__ g_E2,
                                                const float* __restrict__ g_aZ,
                                                const float* __restrict__ g_bZ,
                                                const int* __restrict__ g_k,
                                                float* __restrict__ yH) {
    const int b = blockIdx.x & 63;
    const int q = blockIdx.x >> 6;
    const int head = q >> 2;
    const int cg = q & 3;
    const int bh = b * 4 + head;
    const int c0 = cg * 16;
    const int t = threadIdx.x;

    __shared__ float A[16 * APW];
    __shared__ float segs[16 * 17];
    __shared__ float tot[16];
    __shared__ int   kA[512];
    __shared__ float aZs[512], bZs[512];

    float e1r[2], e2r[2], hv[2][16];
    for (int rr = 0; rr < 2; ++rr) {
        int r = t + rr * 256;
        int j = g_sidx[bh * 512 + r];
        e1r[rr] = g_E1[bh * 512 + r];
        e2r[rr] = g_E2[bh * 512 + r];
        kA[r]  = g_k[bh * 512 + r];
        aZs[r] = g_aZ[bh * 512 + r];
        bZs[r] = g_bZ[bh * 512 + r];
        const float* hp = h + ((size_t)(b * 512 + j) * 4 + head) * 64 + c0;
#pragma unroll
        for (int q4 = 0; q4 < 4; ++q4) {
            float4 v = *(const float4*)(hp + q4 * 4);
            hv[rr][q4 * 4 + 0] = v.x; hv[rr][q4 * 4 + 1] = v.y;
            hv[rr][q4 * 4 + 2] = v.z; hv[rr][q4 * 4 + 3] = v.w;
        }
    }
    __syncthreads();

    // ---- Pass A: suffix table of E1*h ----
    for (int rr = 0; rr < 2; ++rr) {
        int r = t + rr * 256;
#pragma unroll
        for (int c = 0; c < 16; ++c) A[c * APW + r] = e1r[rr] * hv[rr][c];
    }
    __syncthreads();
    {
        int ch = t & 15, seg = t >> 4;
        float* base = A + ch * APW + seg * 32;
        float v[32];
#pragma unroll
        for (int q4 = 0; q4 < 8; ++q4) {
            float4 a = *(const float4*)(base + q4 * 4);
            v[q4 * 4] = a.x; v[q4 * 4 + 1] = a.y; v[q4 * 4 + 2] = a.z; v[q4 * 4 + 3] = a.w;
        }
        float s = 0.f;
#pragma unroll
        for (int i = 0; i < 32; ++i) s += v[i];
        segs[ch * 17 + seg] = s;
        __syncthreads();
        float suf = 0.f;
        for (int s2 = seg + 1; s2 < 16; ++s2) suf += segs[ch * 17 + s2];
        float run = suf;
#pragma unroll
        for (int i = 31; i >= 0; --i) { run += v[i]; v[i] = run; }
#pragma unroll
        for (int q4 = 0; q4 < 8; ++q4)
            *(float4*)(base + q4 * 4) = make_float4(v[q4 * 4], v[q4 * 4 + 1], v[q4 * 4 + 2], v[q4 * 4 + 3]);
    }
    __syncthreads();
    float part[32];
    {
        int cl = t & 15, ibase = t >> 4;
#pragma unroll
        for (int p = 0; p < 32; ++p) {
            int i = p * 16 + ibase;
            int k = kA[i];
            float S1v = (k < 512) ? A[cl * APW + k] : 0.f;
            part[p] = aZs[i] * S1v;
        }
    }
    __syncthreads();

    // ---- Pass B: exclusive-prefix table of E2*h ----
    for (int rr = 0; rr < 2; ++rr) {
        int r = t + rr * 256;
#pragma unroll
        for (int c = 0; c < 16; ++c) A[c * APW + r] = e2r[rr] * hv[rr][c];
    }
    __syncthreads();
    {
        int ch = t & 15, seg = t >> 4;
        float* base = A + ch * APW + seg * 32;
        float v[32];
#pragma unroll
        for (int q4 = 0; q4 < 8; ++q4) {
            float4 a = *(const float4*)(base + q4 * 4);
            v[q4 * 4] = a.x; v[q4 * 4 + 1] = a.y; v[q4 * 4 + 2] = a.z; v[q4 * 4 + 3] = a.w;
        }
        float s = 0.f;
#pragma unroll
        for (int i = 0; i < 32; ++i) s += v[i];
        segs[ch * 17 + seg] = s;
        __syncthreads();
        float pre = 0.f;
        for (int s2 = 0; s2 < seg; ++s2) pre += segs[ch * 17 + s2];
        float run2 = pre;
#pragma unroll
        for (int i = 0; i < 32; ++i) { float tv = v[i]; v[i] = run2; run2 += tv; }
#pragma unroll
        for (int q4 = 0; q4 < 8; ++q4)
            *(float4*)(base + q4 * 4) = make_float4(v[q4 * 4], v[q4 * 4 + 1], v[q4 * 4 + 2], v[q4 * 4 + 3]);
        if (seg == 15) tot[ch] = run2;
    }
    __syncthreads();
    {
        int cl = t & 15, ibase = t >> 4;
#pragma unroll
        for (int p = 0; p < 32; ++p) {
            int i = p * 16 + ibase;
            int k = kA[i];
            float P2 = (k < 512) ? A[cl * APW + k] : tot[cl];
            float val = part[p] + bZs[i] * P2;
            yH[((size_t)(b * 512 + i) * 4 + head) * 64 + c0 + cl] = val;
        }
    }
}

// ---------------------------------------------------------------------------
// Kernel C: x[bn][c] = relu( mean_h yH[bn][h][c] + bias[c] )
// ---------------------------------------------------------------------------
__global__ __launch_bounds__(256) void finalize_kernel(const float* __restrict__ yH,
                                                       const float* __restrict__ bias,
                                                       float* __restrict__ x) {
    int idx = blockIdx.x * 256 + threadIdx.x;
    int bn = idx >> 4, c4 = idx & 15;
    const float* yp = yH + (size_t)bn * 256 + c4 * 4;
    float4 v0 = *(const float4*)(yp);
    float4 v1 = *(const float4*)(yp + 64);
    float4 v2 = *(const float4*)(yp + 128);
    float4 v3 = *(const float4*)(yp + 192);
    float4 bs = *(const float4*)(bias + c4 * 4);
    float4 o;
    o.x = fmaxf(0.25f * (v0.x + v1.x + v2.x + v3.x) + bs.x, 0.f);
    o.y = fmaxf(0.25f * (v0.y + v1.y + v2.y + v3.y) + bs.y, 0.f);
    o.z = fmaxf(0.25f * (v0.z + v1.z + v2.z + v3.z) + bs.z, 0.f);
    o.w = fmaxf(0.25f * (v0.w + v1.w + v2.w + v3.w) + bs.w, 0.f);
    *(float4*)(x + (size_t)bn * 64 + c4 * 4) = o;
}

// ---------------------------------------------------------------------------
// Kernel D: out[b][d] = (mean_n x[b][n][:]) . readout_w[d][:] + readout_b[d]
// ---------------------------------------------------------------------------
__global__ __launch_bounds__(256) void readout_kernel(const float* __restrict__ x,
                                                      const float* __restrict__ rw,
                                                      const float* __restrict__ rb,
                                                      float* __restrict__ out) {
    __shared__ float red[4][64];
    __shared__ float pooled[64];
    int b = blockIdx.x, t = threadIdx.x;
    int c = t & 63, q = t >> 6;
    float acc = 0.f;
    for (int n = q; n < 512; n += 4) acc += x[((size_t)b * 512 + n) * 64 + c];
    red[q][c] = acc;
    __syncthreads();
    if (t < 64) pooled[t] = (red[0][t] + red[1][t] + red[2][t] + red[3][t]) * (1.0f / 512.0f);
    __syncthreads();
    if (t < 64) {
        float a = rb[t];
        for (int cc = 0; cc < 64; ++cc) a += pooled[cc] * rw[t * 64 + cc];
        out[b * 64 + t] = a;
    }
}

extern "C" void kernel_launch(void* const* d_in, const int* in_sizes, int n_in,
                              void* d_out, int out_size, void* d_ws, size_t ws_size,
                              hipStream_t stream) {
    const float* emb       = (const float*)d_in[0];
    const float* lin_w     = (const float*)d_in[1];
    const float* att_src   = (const float*)d_in[2];
    const float* att_dst   = (const float*)d_in[3];
    const float* conv_b    = (const float*)d_in[4];
    const float* readout_w = (const float*)d_in[5];
    const float* readout_b = (const float*)d_in[6];
    float* out = (float*)d_out;

    float* ws   = (float*)d_ws;
    float* xbuf = ws;                  // 2,097,152 floats (8 MB)
    float* hbuf = ws + 2097152;        // 8,388,608 floats (32 MB)

    int*   g_sidx = (int*)xbuf;
    float* g_E1   = xbuf + 131072;
    float* g_E2   = xbuf + 262144;
    float* g_aZ   = xbuf + 393216;
    float* g_bZ   = xbuf + 524288;
    int*   g_k    = (int*)(xbuf + 655360);

    dim3 lin_grid(128, 4);
    for (int l = 0; l < 3; ++l) {
        const float* xin = (l == 0) ? emb : xbuf;
        lin_kernel<<<lin_grid, 256, 0, stream>>>(xin, lin_w + (size_t)l * 16384, hbuf);
        attn_prep<<<256, 256, 0, stream>>>(hbuf, att_src + l * 256, att_dst + l * 256,
                                           g_sidx, g_E1, g_E2, g_aZ, g_bZ, g_k);
        attn_agg<<<1024, 256, 0, stream>>>(hbuf, g_sidx, g_E1, g_E2, g_aZ, g_bZ, g_k, hbuf);
        finalize_kernel<<<2048, 256, 0, stream>>>(hbuf, conv_b + l * 64, xbuf);
    }
    readout_kernel<<<64, 256, 0, stream>>>(xbuf, readout_w, readout_b, out);
}

// Round 6
// 435.058 us; speedup vs baseline: 1.0852x; 1.0852x over previous
//
#include <hip/hip_runtime.h>
#include <math.h>

// Problem constants (fixed by reference): B=64, N=512, D=64, H=4, C=64, L=3
// Workspace layout (floats):
//   xbuf [0 .. 2097152)        : layer activations x (B*N*64) = 8 MB
//     -- prep metadata (3 MB) overlaid at FRONT of xbuf between lin (reads x)
//        and finalize (rewrites x); stream order makes it safe.
//   hbuf [2097152 .. 10485760) : h (B*N*H*C) = 32 MB; yH aliases h.

// ---------------------------------------------------------------------------
// Kernel A v4: h[gn][o] = sum_d x[gn][d] * W[o][d]
// No LDS. Thread owns row gn; x row in 16 float4 VGPRs; W wave-uniform ->
// SGPR broadcast. R5 LESSON: `#pragma unroll 1` on the jc loop made acc[]
// dynamically indexed -> scratch (VGPR=72, WRITE 95MB, 87us). v4: FULLY
// static indexing (all loops unrolled), acc[64]+xr[16] ~140 VGPRs, no spill.
// __launch_bounds__(256,2): 2 waves/EU budget = 256 VGPR cap, 2 blocks/CU.
// ---------------------------------------------------------------------------
__global__ __launch_bounds__(256, 2) void lin_kernel(const float* __restrict__ x,
                                                     const float* __restrict__ W,
                                                     float* __restrict__ h) {
    const int t = threadIdx.x;
    const int gn = blockIdx.x * 256 + t;
    const int o0 = blockIdx.y * 64;

    // x row -> registers (64 VGPRs)
    float4 xr[16];
    const float4* xp = (const float4*)(x + (size_t)gn * 64);
#pragma unroll
    for (int i = 0; i < 16; ++i) xr[i] = xp[i];

    float acc[64];
#pragma unroll
    for (int j = 0; j < 64; ++j) acc[j] = 0.f;

    const float* Wb = W + (size_t)o0 * 64;       // wave-uniform base
#pragma unroll
    for (int jc = 0; jc < 8; ++jc) {             // FULLY unrolled: static idx
#pragma unroll
        for (int d4 = 0; d4 < 16; ++d4) {
            float4 xv = xr[d4];
#pragma unroll
            for (int j = 0; j < 8; ++j) {
                float4 w = *(const float4*)(Wb + (jc * 8 + j) * 64 + d4 * 4); // s_load
                acc[jc * 8 + j] += w.x * xv.x + w.y * xv.y + w.z * xv.z + w.w * xv.w;
            }
        }
    }

    float* hp = h + (size_t)gn * 256 + o0;
#pragma unroll
    for (int q = 0; q < 16; ++q)
        *(float4*)(hp + q * 4) = make_float4(acc[q * 4], acc[q * 4 + 1],
                                             acc[q * 4 + 2], acc[q * 4 + 3]);
}

// ---------------------------------------------------------------------------
// Kernel B1: attn_prep v2 — per (b,head). Shuffle-based bitonic sort (2
// consecutive elements/thread: j=1 in-reg, j<=64 shfl_xor, j in {128,256} via
// LDS -> only 3 barrier-stages vs 45). Wave-shfl scans for z1suf/z2pre.
// ---------------------------------------------------------------------------
__global__ __launch_bounds__(256) void attn_prep(const float* __restrict__ h,
                                                 const float* __restrict__ att_src,
                                                 const float* __restrict__ att_dst,
                                                 int* __restrict__ g_sidx,
                                                 float* __restrict__ g_E1,
                                                 float* __restrict__ g_E2,
                                                 float* __restrict__ g_aZ,
                                                 float* __restrict__ g_bZ,
                                                 int* __restrict__ g_k) {
    const int bh = blockIdx.x;
    const int b = bh >> 2;
    const int head = bh & 3;
    const int t = threadIdx.x;
    const int lane = t & 63;
    const int wid = t >> 6;

    __shared__ float att_s[64], att_d[64];
    __shared__ float s_val[512];
    __shared__ int   s_idxE[512];
    __shared__ float dArr[512];
    __shared__ float z1suf[513], z2pre[513];
    __shared__ float wred[8];

    if (t < 64) att_s[t] = att_src[head * 64 + t];
    else if (t < 128) att_d[t - 64] = att_dst[head * 64 + (t - 64)];
    __syncthreads();

    for (int rr = 0; rr < 2; ++rr) {
        int j = t + rr * 256;
        const float* hrow = h + ((size_t)(b * 512 + j) * 4 + head) * 64;
        float as = 0.f, ad = 0.f;
#pragma unroll
        for (int d4 = 0; d4 < 16; ++d4) {
            float4 hv = *(const float4*)(hrow + d4 * 4);
            float4 sv = *(const float4*)(att_s + d4 * 4);
            float4 dv = *(const float4*)(att_d + d4 * 4);
            as += hv.x * sv.x + hv.y * sv.y + hv.z * sv.z + hv.w * sv.w;
            ad += hv.x * dv.x + hv.y * dv.y + hv.z * dv.z + hv.w * dv.w;
        }
        s_val[j] = as; dArr[j] = ad;
    }
    __syncthreads();

    // Bitonic sort ascending; thread t holds positions 2t, 2t+1.
    float v0 = s_val[2 * t], v1 = s_val[2 * t + 1];
    int id0 = 2 * t, id1 = 2 * t + 1;
    for (int k = 2; k <= 512; k <<= 1) {
        for (int j = k >> 1; j >= 1; j >>= 1) {
            bool asc = ((t & (k >> 1)) == 0);
            if (j == 1) {
                bool sw = asc ? (v0 > v1) : (v0 < v1);
                if (sw) { float tv = v0; v0 = v1; v1 = tv; int ti = id0; id0 = id1; id1 = ti; }
            } else if (j <= 64) {
                int m = j >> 1;
                float w0 = __shfl_xor(v0, m, 64);
                int  wi0 = __shfl_xor(id0, m, 64);
                float w1 = __shfl_xor(v1, m, 64);
                int  wi1 = __shfl_xor(id1, m, 64);
                bool low = ((t & m) == 0);
                bool wantmin = (low == asc);
                if (wantmin ? (w0 < v0) : (w0 > v0)) { v0 = w0; id0 = wi0; }
                if (wantmin ? (w1 < v1) : (w1 > v1)) { v1 = w1; id1 = wi1; }
            } else {
                int m = j >> 1;
                s_val[2 * t] = v0; s_val[2 * t + 1] = v1;
                s_idxE[2 * t] = id0; s_idxE[2 * t + 1] = id1;
                __syncthreads();
                int tp = t ^ m;
                float w0 = s_val[2 * tp], w1 = s_val[2 * tp + 1];
                int wi0 = s_idxE[2 * tp], wi1 = s_idxE[2 * tp + 1];
                bool low = ((t & m) == 0);
                bool wantmin = (low == asc);
                if (wantmin ? (w0 < v0) : (w0 > v0)) { v0 = w0; id0 = wi0; }
                if (wantmin ? (w1 < v1) : (w1 > v1)) { v1 = w1; id1 = wi1; }
                __syncthreads();
            }
        }
    }

    s_val[2 * t] = v0; s_val[2 * t + 1] = v1;
    __syncthreads();
    const float M = s_val[511];
    float e1_0 = __expf(v0 - M), e1_1 = __expf(v1 - M);
    float e2_0 = __expf(0.2f * (v0 - M)), e2_1 = __expf(0.2f * (v1 - M));
    *(float2*)(g_E1 + bh * 512 + 2 * t) = make_float2(e1_0, e1_1);
    *(float2*)(g_E2 + bh * 512 + 2 * t) = make_float2(e2_0, e2_1);
    *(int2*)(g_sidx + bh * 512 + 2 * t) = make_int2(id0, id1);

    float S1 = e1_0 + e1_1, S2 = e2_0 + e2_1;
    float i1 = S1, i2 = S2;
    for (int off = 1; off < 64; off <<= 1) {
        float u1 = __shfl_up(i1, off, 64);
        float u2 = __shfl_up(i2, off, 64);
        if (lane >= off) { i1 += u1; i2 += u2; }
    }
    if (lane == 63) { wred[wid] = i1; wred[4 + wid] = i2; }
    __syncthreads();
    float off1 = 0.f, off2 = 0.f;
    for (int w = 0; w < wid; ++w) { off1 += wred[w]; off2 += wred[4 + w]; }
    const float T1 = wred[0] + wred[1] + wred[2] + wred[3];
    const float T2 = wred[4] + wred[5] + wred[6] + wred[7];
    float pre1 = off1 + i1 - S1;
    float pre2 = off2 + i2 - S2;
    z1suf[2 * t] = T1 - pre1;
    z1suf[2 * t + 1] = T1 - pre1 - e1_0;
    z2pre[2 * t] = pre2;
    z2pre[2 * t + 1] = pre2 + e2_0;
    if (t == 0) { z1suf[512] = 0.f; z2pre[512] = T2; }
    __syncthreads();

    for (int rr = 0; rr < 2; ++rr) {
        int i = t + rr * 256;
        float d = dArr[i];
        int lo = 0, hi = 512;
        while (lo < hi) {
            int mid = (lo + hi) >> 1;
            if (d + s_val[mid] >= 0.f) hi = mid; else lo = mid + 1;
        }
        int k = lo;
        float g = d + M;
        float G = (g >= 0.f) ? g : 0.2f * g;
        float al = __expf(g - G);
        float be = __expf(0.2f * g - G);
        float Z = al * z1suf[k] + be * z2pre[k];
        float inv = 1.0f / Z;
        g_aZ[bh * 512 + i] = al * inv;
        g_bZ[bh * 512 + i] = be * inv;
        g_k[bh * 512 + i]  = k;
    }
}

// ---------------------------------------------------------------------------
// Kernel B2: attn_agg v2 — 16 channels/block (grid 1024). 64-B aligned h
// gather held in registers; ONE 33-KB LDS table used twice. XCD swizzle:
// blockIdx = q*64 + b so all 16 blocks of a batch share an XCD.
// yH aliases h: all h reads (phase 0) precede yH writes (end), block-local.
// ---------------------------------------------------------------------------
#define APW 516
__global__ __launch_bounds__(256) void attn_agg(const float* __restrict__ h,
                                                const int* __restrict__ g_sidx,
                                                const float* __restrict__ g_E1,
                                                const float* __restrict__ g_E2,
                                                const float* __restrict__ g_aZ,
                                                const float* __restrict__ g_bZ,
                                                const int* __restrict__ g_k,
                                                float* __restrict__ yH) {
    const int b = blockIdx.x & 63;
    const int q = blockIdx.x >> 6;
    const int head = q >> 2;
    const int cg = q & 3;
    const int bh = b * 4 + head;
    const int c0 = cg * 16;
    const int t = threadIdx.x;

    __shared__ float A[16 * APW];
    __shared__ float segs[16 * 17];
    __shared__ float tot[16];
    __shared__ int   kA[512];
    __shared__ float aZs[512], bZs[512];

    float e1r[2], e2r[2], hv[2][16];
    for (int rr = 0; rr < 2; ++rr) {
        int r = t + rr * 256;
        int j = g_sidx[bh * 512 + r];
        e1r[rr] = g_E1[bh * 512 + r];
        e2r[rr] = g_E2[bh * 512 + r];
        kA[r]  = g_k[bh * 512 + r];
        aZs[r] = g_aZ[bh * 512 + r];
        bZs[r] = g_bZ[bh * 512 + r];
        const float* hp = h + ((size_t)(b * 512 + j) * 4 + head) * 64 + c0;
#pragma unroll
        for (int q4 = 0; q4 < 4; ++q4) {
            float4 v = *(const float4*)(hp + q4 * 4);
            hv[rr][q4 * 4 + 0] = v.x; hv[rr][q4 * 4 + 1] = v.y;
            hv[rr][q4 * 4 + 2] = v.z; hv[rr][q4 * 4 + 3] = v.w;
        }
    }
    __syncthreads();

    // ---- Pass A: suffix table of E1*h ----
    for (int rr = 0; rr < 2; ++rr) {
        int r = t + rr * 256;
#pragma unroll
        for (int c = 0; c < 16; ++c) A[c * APW + r] = e1r[rr] * hv[rr][c];
    }
    __syncthreads();
    {
        int ch = t & 15, seg = t >> 4;
        float* base = A + ch * APW + seg * 32;
        float v[32];
#pragma unroll
        for (int q4 = 0; q4 < 8; ++q4) {
            float4 a = *(const float4*)(base + q4 * 4);
            v[q4 * 4] = a.x; v[q4 * 4 + 1] = a.y; v[q4 * 4 + 2] = a.z; v[q4 * 4 + 3] = a.w;
        }
        float s = 0.f;
#pragma unroll
        for (int i = 0; i < 32; ++i) s += v[i];
        segs[ch * 17 + seg] = s;
        __syncthreads();
        float suf = 0.f;
        for (int s2 = seg + 1; s2 < 16; ++s2) suf += segs[ch * 17 + s2];
        float run = suf;
#pragma unroll
        for (int i = 31; i >= 0; --i) { run += v[i]; v[i] = run; }
#pragma unroll
        for (int q4 = 0; q4 < 8; ++q4)
            *(float4*)(base + q4 * 4) = make_float4(v[q4 * 4], v[q4 * 4 + 1], v[q4 * 4 + 2], v[q4 * 4 + 3]);
    }
    __syncthreads();
    float part[32];
    {
        int cl = t & 15, ibase = t >> 4;
#pragma unroll
        for (int p = 0; p < 32; ++p) {
            int i = p * 16 + ibase;
            int k = kA[i];
            float S1v = (k < 512) ? A[cl * APW + k] : 0.f;
            part[p] = aZs[i] * S1v;
        }
    }
    __syncthreads();

    // ---- Pass B: exclusive-prefix table of E2*h ----
    for (int rr = 0; rr < 2; ++rr) {
        int r = t + rr * 256;
#pragma unroll
        for (int c = 0; c < 16; ++c) A[c * APW + r] = e2r[rr] * hv[rr][c];
    }
    __syncthreads();
    {
        int ch = t & 15, seg = t >> 4;
        float* base = A + ch * APW + seg * 32;
        float v[32];
#pragma unroll
        for (int q4 = 0; q4 < 8; ++q4) {
            float4 a = *(const float4*)(base + q4 * 4);
            v[q4 * 4] = a.x; v[q4 * 4 + 1] = a.y; v[q4 * 4 + 2] = a.z; v[q4 * 4 + 3] = a.w;
        }
        float s = 0.f;
#pragma unroll
        for (int i = 0; i < 32; ++i) s += v[i];
        segs[ch * 17 + seg] = s;
        __syncthreads();
        float pre = 0.f;
        for (int s2 = 0; s2 < seg; ++s2) pre += segs[ch * 17 + s2];
        float run2 = pre;
#pragma unroll
        for (int i = 0; i < 32; ++i) { float tv = v[i]; v[i] = run2; run2 += tv; }
#pragma unroll
        for (int q4 = 0; q4 < 8; ++q4)
            *(float4*)(base + q4 * 4) = make_float4(v[q4 * 4], v[q4 * 4 + 1], v[q4 * 4 + 2], v[q4 * 4 + 3]);
        if (seg == 15) tot[ch] = run2;
    }
    __syncthreads();
    {
        int cl = t & 15, ibase = t >> 4;
#pragma unroll
        for (int p = 0; p < 32; ++p) {
            int i = p * 16 + ibase;
            int k = kA[i];
            float P2 = (k < 512) ? A[cl * APW + k] : tot[cl];
            float val = part[p] + bZs[i] * P2;
            yH[((size_t)(b * 512 + i) * 4 + head) * 64 + c0 + cl] = val;
        }
    }
}

// ---------------------------------------------------------------------------
// Kernel C: x[bn][c] = relu( mean_h yH[bn][h][c] + bias[c] )
// ---------------------------------------------------------------------------
__global__ __launch_bounds__(256) void finalize_kernel(const float* __restrict__ yH,
                                                       const float* __restrict__ bias,
                                                       float* __restrict__ x) {
    int idx = blockIdx.x * 256 + threadIdx.x;
    int bn = idx >> 4, c4 = idx & 15;
    const float* yp = yH + (size_t)bn * 256 + c4 * 4;
    float4 v0 = *(const float4*)(yp);
    float4 v1 = *(const float4*)(yp + 64);
    float4 v2 = *(const float4*)(yp + 128);
    float4 v3 = *(const float4*)(yp + 192);
    float4 bs = *(const float4*)(bias + c4 * 4);
    float4 o;
    o.x = fmaxf(0.25f * (v0.x + v1.x + v2.x + v3.x) + bs.x, 0.f);
    o.y = fmaxf(0.25f * (v0.y + v1.y + v2.y + v3.y) + bs.y, 0.f);
    o.z = fmaxf(0.25f * (v0.z + v1.z + v2.z + v3.z) + bs.z, 0.f);
    o.w = fmaxf(0.25f * (v0.w + v1.w + v2.w + v3.w) + bs.w, 0.f);
    *(float4*)(x + (size_t)bn * 64 + c4 * 4) = o;
}

// ---------------------------------------------------------------------------
// Kernel D: out[b][d] = (mean_n x[b][n][:]) . readout_w[d][:] + readout_b[d]
// ---------------------------------------------------------------------------
__global__ __launch_bounds__(256) void readout_kernel(const float* __restrict__ x,
                                                      const float* __restrict__ rw,
                                                      const float* __restrict__ rb,
                                                      float* __restrict__ out) {
    __shared__ float red[4][64];
    __shared__ float pooled[64];
    int b = blockIdx.x, t = threadIdx.x;
    int c = t & 63, q = t >> 6;
    float acc = 0.f;
    for (int n = q; n < 512; n += 4) acc += x[((size_t)b * 512 + n) * 64 + c];
    red[q][c] = acc;
    __syncthreads();
    if (t < 64) pooled[t] = (red[0][t] + red[1][t] + red[2][t] + red[3][t]) * (1.0f / 512.0f);
    __syncthreads();
    if (t < 64) {
        float a = rb[t];
        for (int cc = 0; cc < 64; ++cc) a += pooled[cc] * rw[t * 64 + cc];
        out[b * 64 + t] = a;
    }
}

extern "C" void kernel_launch(void* const* d_in, const int* in_sizes, int n_in,
                              void* d_out, int out_size, void* d_ws, size_t ws_size,
                              hipStream_t stream) {
    const float* emb       = (const float*)d_in[0];
    const float* lin_w     = (const float*)d_in[1];
    const float* att_src   = (const float*)d_in[2];
    const float* att_dst   = (const float*)d_in[3];
    const float* conv_b    = (const float*)d_in[4];
    const float* readout_w = (const float*)d_in[5];
    const float* readout_b = (const float*)d_in[6];
    float* out = (float*)d_out;

    float* ws   = (float*)d_ws;
    float* xbuf = ws;                  // 2,097,152 floats (8 MB)
    float* hbuf = ws + 2097152;        // 8,388,608 floats (32 MB)

    int*   g_sidx = (int*)xbuf;
    float* g_E1   = xbuf + 131072;
    float* g_E2   = xbuf + 262144;
    float* g_aZ   = xbuf + 393216;
    float* g_bZ   = xbuf + 524288;
    int*   g_k    = (int*)(xbuf + 655360);

    dim3 lin_grid(128, 4);
    for (int l = 0; l < 3; ++l) {
        const float* xin = (l == 0) ? emb : xbuf;
        lin_kernel<<<lin_grid, 256, 0, stream>>>(xin, lin_w + (size_t)l * 16384, hbuf);
        attn_prep<<<256, 256, 0, stream>>>(hbuf, att_src + l * 256, att_dst + l * 256,
                                           g_sidx, g_E1, g_E2, g_aZ, g_bZ, g_k);
        attn_agg<<<1024, 256, 0, stream>>>(hbuf, g_sidx, g_E1, g_E2, g_aZ, g_bZ, g_k, hbuf);
        finalize_kernel<<<2048, 256, 0, stream>>>(hbuf, conv_b + l * 64, xbuf);
    }
    readout_kernel<<<64, 256, 0, stream>>>(xbuf, readout_w, readout_b, out);
}

// Round 7
// 434.835 us; speedup vs baseline: 1.0857x; 1.0005x over previous
//
#include <hip/hip_runtime.h>
#include <math.h>

// Problem constants (fixed by reference): B=64, N=512, D=64, H=4, C=64, L=3
// Workspace layout (floats):
//   xbuf [0 .. 2097152)        : layer activations x (B*N*64) = 8 MB
//     -- prep metadata (3 MB) overlaid at FRONT of xbuf between lin (reads x)
//        and finalize (rewrites x); stream order makes it safe.
//   hbuf [2097152 .. 10485760) : h (B*N*H*C) = 32 MB; yH aliases h.

// ---------------------------------------------------------------------------
// Kernel A v5: h[gn][o] = sum_d x[gn][d] * W[o][d]
// No LDS; x row in 16 float4 VGPRs; W wave-uniform -> SGPR broadcast.
// R6 LESSON: 64-output chunks (16 KB W) thrashed the ~16 KB scalar K$ and
// grid 512 gave only 2 waves/SIMD -> 70% scalar-stall (VALUBusy 30%, 74us).
// v5: o-chunk = 32 (8 KB, K$-resident), grid 1024 = 4 blocks/CU, and o-chunk
// in LOW bits of blockIdx so a CU's 4 round-robin blocks (c, c+256, ...)
// share the SAME W chunk. acc[32]+xr[16] ~115 VGPR, launch_bounds(256,4).
// All indexing static (R5 lesson: dynamic acc idx -> scratch).
// ---------------------------------------------------------------------------
__global__ __launch_bounds__(256, 4) void lin_kernel(const float* __restrict__ x,
                                                     const float* __restrict__ W,
                                                     float* __restrict__ h) {
    const int t = threadIdx.x;
    const int oc = blockIdx.x & 7;        // o-chunk (low bits: co-resident share)
    const int rb = blockIdx.x >> 3;       // row block 0..127
    const int gn = rb * 256 + t;
    const int o0 = oc * 32;

    // x row -> registers (64 VGPRs)
    float4 xr[16];
    const float4* xp = (const float4*)(x + (size_t)gn * 64);
#pragma unroll
    for (int i = 0; i < 16; ++i) xr[i] = xp[i];

    float acc[32];
#pragma unroll
    for (int j = 0; j < 32; ++j) acc[j] = 0.f;

    const float* Wb = W + (size_t)o0 * 64;        // wave-uniform base
#pragma unroll
    for (int jc = 0; jc < 4; ++jc) {              // fully static indexing
#pragma unroll
        for (int d4 = 0; d4 < 16; ++d4) {
            float4 xv = xr[d4];
#pragma unroll
            for (int j = 0; j < 8; ++j) {
                float4 w = *(const float4*)(Wb + (jc * 8 + j) * 64 + d4 * 4); // s_load
                acc[jc * 8 + j] += w.x * xv.x + w.y * xv.y + w.z * xv.z + w.w * xv.w;
            }
        }
    }

    float* hp = h + (size_t)gn * 256 + o0;
#pragma unroll
    for (int q = 0; q < 8; ++q)
        *(float4*)(hp + q * 4) = make_float4(acc[q * 4], acc[q * 4 + 1],
                                             acc[q * 4 + 2], acc[q * 4 + 3]);
}

// ---------------------------------------------------------------------------
// Kernel B1: attn_prep v2 — per (b,head). Shuffle-based bitonic sort (2
// consecutive elements/thread: j=1 in-reg, j<=64 shfl_xor, j in {128,256} via
// LDS -> only 3 barrier-stages vs 45). Wave-shfl scans for z1suf/z2pre.
// ---------------------------------------------------------------------------
__global__ __launch_bounds__(256) void attn_prep(const float* __restrict__ h,
                                                 const float* __restrict__ att_src,
                                                 const float* __restrict__ att_dst,
                                                 int* __restrict__ g_sidx,
                                                 float* __restrict__ g_E1,
                                                 float* __restrict__ g_E2,
                                                 float* __restrict__ g_aZ,
                                                 float* __restrict__ g_bZ,
                                                 int* __restrict__ g_k) {
    const int bh = blockIdx.x;
    const int b = bh >> 2;
    const int head = bh & 3;
    const int t = threadIdx.x;
    const int lane = t & 63;
    const int wid = t >> 6;

    __shared__ float att_s[64], att_d[64];
    __shared__ float s_val[512];
    __shared__ int   s_idxE[512];
    __shared__ float dArr[512];
    __shared__ float z1suf[513], z2pre[513];
    __shared__ float wred[8];

    if (t < 64) att_s[t] = att_src[head * 64 + t];
    else if (t < 128) att_d[t - 64] = att_dst[head * 64 + (t - 64)];
    __syncthreads();

    for (int rr = 0; rr < 2; ++rr) {
        int j = t + rr * 256;
        const float* hrow = h + ((size_t)(b * 512 + j) * 4 + head) * 64;
        float as = 0.f, ad = 0.f;
#pragma unroll
        for (int d4 = 0; d4 < 16; ++d4) {
            float4 hv = *(const float4*)(hrow + d4 * 4);
            float4 sv = *(const float4*)(att_s + d4 * 4);
            float4 dv = *(const float4*)(att_d + d4 * 4);
            as += hv.x * sv.x + hv.y * sv.y + hv.z * sv.z + hv.w * sv.w;
            ad += hv.x * dv.x + hv.y * dv.y + hv.z * dv.z + hv.w * dv.w;
        }
        s_val[j] = as; dArr[j] = ad;
    }
    __syncthreads();

    // Bitonic sort ascending; thread t holds positions 2t, 2t+1.
    float v0 = s_val[2 * t], v1 = s_val[2 * t + 1];
    int id0 = 2 * t, id1 = 2 * t + 1;
    for (int k = 2; k <= 512; k <<= 1) {
        for (int j = k >> 1; j >= 1; j >>= 1) {
            bool asc = ((t & (k >> 1)) == 0);
            if (j == 1) {
                bool sw = asc ? (v0 > v1) : (v0 < v1);
                if (sw) { float tv = v0; v0 = v1; v1 = tv; int ti = id0; id0 = id1; id1 = ti; }
            } else if (j <= 64) {
                int m = j >> 1;
                float w0 = __shfl_xor(v0, m, 64);
                int  wi0 = __shfl_xor(id0, m, 64);
                float w1 = __shfl_xor(v1, m, 64);
                int  wi1 = __shfl_xor(id1, m, 64);
                bool low = ((t & m) == 0);
                bool wantmin = (low == asc);
                if (wantmin ? (w0 < v0) : (w0 > v0)) { v0 = w0; id0 = wi0; }
                if (wantmin ? (w1 < v1) : (w1 > v1)) { v1 = w1; id1 = wi1; }
            } else {
                int m = j >> 1;
                s_val[2 * t] = v0; s_val[2 * t + 1] = v1;
                s_idxE[2 * t] = id0; s_idxE[2 * t + 1] = id1;
                __syncthreads();
                int tp = t ^ m;
                float w0 = s_val[2 * tp], w1 = s_val[2 * tp + 1];
                int wi0 = s_idxE[2 * tp], wi1 = s_idxE[2 * tp + 1];
                bool low = ((t & m) == 0);
                bool wantmin = (low == asc);
                if (wantmin ? (w0 < v0) : (w0 > v0)) { v0 = w0; id0 = wi0; }
                if (wantmin ? (w1 < v1) : (w1 > v1)) { v1 = w1; id1 = wi1; }
                __syncthreads();
            }
        }
    }

    s_val[2 * t] = v0; s_val[2 * t + 1] = v1;
    __syncthreads();
    const float M = s_val[511];
    float e1_0 = __expf(v0 - M), e1_1 = __expf(v1 - M);
    float e2_0 = __expf(0.2f * (v0 - M)), e2_1 = __expf(0.2f * (v1 - M));
    *(float2*)(g_E1 + bh * 512 + 2 * t) = make_float2(e1_0, e1_1);
    *(float2*)(g_E2 + bh * 512 + 2 * t) = make_float2(e2_0, e2_1);
    *(int2*)(g_sidx + bh * 512 + 2 * t) = make_int2(id0, id1);

    float S1 = e1_0 + e1_1, S2 = e2_0 + e2_1;
    float i1 = S1, i2 = S2;
    for (int off = 1; off < 64; off <<= 1) {
        float u1 = __shfl_up(i1, off, 64);
        float u2 = __shfl_up(i2, off, 64);
        if (lane >= off) { i1 += u1; i2 += u2; }
    }
    if (lane == 63) { wred[wid] = i1; wred[4 + wid] = i2; }
    __syncthreads();
    float off1 = 0.f, off2 = 0.f;
    for (int w = 0; w < wid; ++w) { off1 += wred[w]; off2 += wred[4 + w]; }
    const float T1 = wred[0] + wred[1] + wred[2] + wred[3];
    const float T2 = wred[4] + wred[5] + wred[6] + wred[7];
    float pre1 = off1 + i1 - S1;
    float pre2 = off2 + i2 - S2;
    z1suf[2 * t] = T1 - pre1;
    z1suf[2 * t + 1] = T1 - pre1 - e1_0;
    z2pre[2 * t] = pre2;
    z2pre[2 * t + 1] = pre2 + e2_0;
    if (t == 0) { z1suf[512] = 0.f; z2pre[512] = T2; }
    __syncthreads();

    for (int rr = 0; rr < 2; ++rr) {
        int i = t + rr * 256;
        float d = dArr[i];
        int lo = 0, hi = 512;
        while (lo < hi) {
            int mid = (lo + hi) >> 1;
            if (d + s_val[mid] >= 0.f) hi = mid; else lo = mid + 1;
        }
        int k = lo;
        float g = d + M;
        float G = (g >= 0.f) ? g : 0.2f * g;
        float al = __expf(g - G);
        float be = __expf(0.2f * g - G);
        float Z = al * z1suf[k] + be * z2pre[k];
        float inv = 1.0f / Z;
        g_aZ[bh * 512 + i] = al * inv;
        g_bZ[bh * 512 + i] = be * inv;
        g_k[bh * 512 + i]  = k;
    }
}

// ---------------------------------------------------------------------------
// Kernel B2: attn_agg v2 — 16 channels/block (grid 1024). 64-B aligned h
// gather held in registers; ONE 33-KB LDS table used twice. XCD swizzle:
// blockIdx = q*64 + b so all 16 blocks of a batch share an XCD.
// yH aliases h: all h reads (phase 0) precede yH writes (end), block-local.
// ---------------------------------------------------------------------------
#define APW 516
__global__ __launch_bounds__(256) void attn_agg(const float* __restrict__ h,
                                                const int* __restrict__ g_sidx,
                                                const float* __restrict__ g_E1,
                                                const float* __restrict__ g_E2,
                                                const float* __restrict__ g_aZ,
                                                const float* __restrict__ g_bZ,
                                                const int* __restrict__ g_k,
                                                float* __restrict__ yH) {
    const int b = blockIdx.x & 63;
    const int q = blockIdx.x >> 6;
    const int head = q >> 2;
    const int cg = q & 3;
    const int bh = b * 4 + head;
    const int c0 = cg * 16;
    const int t = threadIdx.x;

    __shared__ float A[16 * APW];
    __shared__ float segs[16 * 17];
    __shared__ float tot[16];
    __shared__ int   kA[512];
    __shared__ float aZs[512], bZs[512];

    float e1r[2], e2r[2], hv[2][16];
    for (int rr = 0; rr < 2; ++rr) {
        int r = t + rr * 256;
        int j = g_sidx[bh * 512 + r];
        e1r[rr] = g_E1[bh * 512 + r];
        e2r[rr] = g_E2[bh * 512 + r];
        kA[r]  = g_k[bh * 512 + r];
        aZs[r] = g_aZ[bh * 512 + r];
        bZs[r] = g_bZ[bh * 512 + r];
        const float* hp = h + ((size_t)(b * 512 + j) * 4 + head) * 64 + c0;
#pragma unroll
        for (int q4 = 0; q4 < 4; ++q4) {
            float4 v = *(const float4*)(hp + q4 * 4);
            hv[rr][q4 * 4 + 0] = v.x; hv[rr][q4 * 4 + 1] = v.y;
            hv[rr][q4 * 4 + 2] = v.z; hv[rr][q4 * 4 + 3] = v.w;
        }
    }
    __syncthreads();

    // ---- Pass A: suffix table of E1*h ----
    for (int rr = 0; rr < 2; ++rr) {
        int r = t + rr * 256;
#pragma unroll
        for (int c = 0; c < 16; ++c) A[c * APW + r] = e1r[rr] * hv[rr][c];
    }
    __syncthreads();
    {
        int ch = t & 15, seg = t >> 4;
        float* base = A + ch * APW + seg * 32;
        float v[32];
#pragma unroll
        for (int q4 = 0; q4 < 8; ++q4) {
            float4 a = *(const float4*)(base + q4 * 4);
            v[q4 * 4] = a.x; v[q4 * 4 + 1] = a.y; v[q4 * 4 + 2] = a.z; v[q4 * 4 + 3] = a.w;
        }
        float s = 0.f;
#pragma unroll
        for (int i = 0; i < 32; ++i) s += v[i];
        segs[ch * 17 + seg] = s;
        __syncthreads();
        float suf = 0.f;
        for (int s2 = seg + 1; s2 < 16; ++s2) suf += segs[ch * 17 + s2];
        float run = suf;
#pragma unroll
        for (int i = 31; i >= 0; --i) { run += v[i]; v[i] = run; }
#pragma unroll
        for (int q4 = 0; q4 < 8; ++q4)
            *(float4*)(base + q4 * 4) = make_float4(v[q4 * 4], v[q4 * 4 + 1], v[q4 * 4 + 2], v[q4 * 4 + 3]);
    }
    __syncthreads();
    float part[32];
    {
        int cl = t & 15, ibase = t >> 4;
#pragma unroll
        for (int p = 0; p < 32; ++p) {
            int i = p * 16 + ibase;
            int k = kA[i];
            float S1v = (k < 512) ? A[cl * APW + k] : 0.f;
            part[p] = aZs[i] * S1v;
        }
    }
    __syncthreads();

    // ---- Pass B: exclusive-prefix table of E2*h ----
    for (int rr = 0; rr < 2; ++rr) {
        int r = t + rr * 256;
#pragma unroll
        for (int c = 0; c < 16; ++c) A[c * APW + r] = e2r[rr] * hv[rr][c];
    }
    __syncthreads();
    {
        int ch = t & 15, seg = t >> 4;
        float* base = A + ch * APW + seg * 32;
        float v[32];
#pragma unroll
        for (int q4 = 0; q4 < 8; ++q4) {
            float4 a = *(const float4*)(base + q4 * 4);
            v[q4 * 4] = a.x; v[q4 * 4 + 1] = a.y; v[q4 * 4 + 2] = a.z; v[q4 * 4 + 3] = a.w;
        }
        float s = 0.f;
#pragma unroll
        for (int i = 0; i < 32; ++i) s += v[i];
        segs[ch * 17 + seg] = s;
        __syncthreads();
        float pre = 0.f;
        for (int s2 = 0; s2 < seg; ++s2) pre += segs[ch * 17 + s2];
        float run2 = pre;
#pragma unroll
        for (int i = 0; i < 32; ++i) { float tv = v[i]; v[i] = run2; run2 += tv; }
#pragma unroll
        for (int q4 = 0; q4 < 8; ++q4)
            *(float4*)(base + q4 * 4) = make_float4(v[q4 * 4], v[q4 * 4 + 1], v[q4 * 4 + 2], v[q4 * 4 + 3]);
        if (seg == 15) tot[ch] = run2;
    }
    __syncthreads();
    {
        int cl = t & 15, ibase = t >> 4;
#pragma unroll
        for (int p = 0; p < 32; ++p) {
            int i = p * 16 + ibase;
            int k = kA[i];
            float P2 = (k < 512) ? A[cl * APW + k] : tot[cl];
            float val = part[p] + bZs[i] * P2;
            yH[((size_t)(b * 512 + i) * 4 + head) * 64 + c0 + cl] = val;
        }
    }
}

// ---------------------------------------------------------------------------
// Kernel C: x[bn][c] = relu( mean_h yH[bn][h][c] + bias[c] )
// ---------------------------------------------------------------------------
__global__ __launch_bounds__(256) void finalize_kernel(const float* __restrict__ yH,
                                                       const float* __restrict__ bias,
                                                       float* __restrict__ x) {
    int idx = blockIdx.x * 256 + threadIdx.x;
    int bn = idx >> 4, c4 = idx & 15;
    const float* yp = yH + (size_t)bn * 256 + c4 * 4;
    float4 v0 = *(const float4*)(yp);
    float4 v1 = *(const float4*)(yp + 64);
    float4 v2 = *(const float4*)(yp + 128);
    float4 v3 = *(const float4*)(yp + 192);
    float4 bs = *(const float4*)(bias + c4 * 4);
    float4 o;
    o.x = fmaxf(0.25f * (v0.x + v1.x + v2.x + v3.x) + bs.x, 0.f);
    o.y = fmaxf(0.25f * (v0.y + v1.y + v2.y + v3.y) + bs.y, 0.f);
    o.z = fmaxf(0.25f * (v0.z + v1.z + v2.z + v3.z) + bs.z, 0.f);
    o.w = fmaxf(0.25f * (v0.w + v1.w + v2.w + v3.w) + bs.w, 0.f);
    *(float4*)(x + (size_t)bn * 64 + c4 * 4) = o;
}

// ---------------------------------------------------------------------------
// Kernel D: out[b][d] = (mean_n x[b][n][:]) . readout_w[d][:] + readout_b[d]
// ---------------------------------------------------------------------------
__global__ __launch_bounds__(256) void readout_kernel(const float* __restrict__ x,
                                                      const float* __restrict__ rw,
                                                      const float* __restrict__ rb,
                                                      float* __restrict__ out) {
    __shared__ float red[4][64];
    __shared__ float pooled[64];
    int b = blockIdx.x, t = threadIdx.x;
    int c = t & 63, q = t >> 6;
    float acc = 0.f;
    for (int n = q; n < 512; n += 4) acc += x[((size_t)b * 512 + n) * 64 + c];
    red[q][c] = acc;
    __syncthreads();
    if (t < 64) pooled[t] = (red[0][t] + red[1][t] + red[2][t] + red[3][t]) * (1.0f / 512.0f);
    __syncthreads();
    if (t < 64) {
        float a = rb[t];
        for (int cc = 0; cc < 64; ++cc) a += pooled[cc] * rw[t * 64 + cc];
        out[b * 64 + t] = a;
    }
}

extern "C" void kernel_launch(void* const* d_in, const int* in_sizes, int n_in,
                              void* d_out, int out_size, void* d_ws, size_t ws_size,
                              hipStream_t stream) {
    const float* emb       = (const float*)d_in[0];
    const float* lin_w     = (const float*)d_in[1];
    const float* att_src   = (const float*)d_in[2];
    const float* att_dst   = (const float*)d_in[3];
    const float* conv_b    = (const float*)d_in[4];
    const float* readout_w = (const float*)d_in[5];
    const float* readout_b = (const float*)d_in[6];
    float* out = (float*)d_out;

    float* ws   = (float*)d_ws;
    float* xbuf = ws;                  // 2,097,152 floats (8 MB)
    float* hbuf = ws + 2097152;        // 8,388,608 floats (32 MB)

    int*   g_sidx = (int*)xbuf;
    float* g_E1   = xbuf + 131072;
    float* g_E2   = xbuf + 262144;
    float* g_aZ   = xbuf + 393216;
    float* g_bZ   = xbuf + 524288;
    int*   g_k    = (int*)(xbuf + 655360);

    for (int l = 0; l < 3; ++l) {
        const float* xin = (l == 0) ? emb : xbuf;
        lin_kernel<<<1024, 256, 0, stream>>>(xin, lin_w + (size_t)l * 16384, hbuf);
        attn_prep<<<256, 256, 0, stream>>>(hbuf, att_src + l * 256, att_dst + l * 256,
                                           g_sidx, g_E1, g_E2, g_aZ, g_bZ, g_k);
        attn_agg<<<1024, 256, 0, stream>>>(hbuf, g_sidx, g_E1, g_E2, g_aZ, g_bZ, g_k, hbuf);
        finalize_kernel<<<2048, 256, 0, stream>>>(hbuf, conv_b + l * 64, xbuf);
    }
    readout_kernel<<<64, 256, 0, stream>>>(xbuf, readout_w, readout_b, out);
}

// Round 8
// 321.654 us; speedup vs baseline: 1.4677x; 1.3519x over previous
//
#include <hip/hip_runtime.h>
#include <math.h>

// Problem constants (fixed by reference): B=64, N=512, D=64, H=4, C=64, L=3
// Workspace layout (floats):
//   xbuf [0 .. 2097152)        : layer activations x (B*N*64) = 8 MB
//     -- prep metadata (3 MB) overlaid at FRONT of xbuf between lin (reads x)
//        and finalize (rewrites x); stream order makes it safe.
//   hbuf [2097152 .. 10485760) : h (B*N*H*C) = 32 MB; yH aliases h.

// ---------------------------------------------------------------------------
// Kernel A (reverted to R2 proven version): h[gn][o] = sum_d x[gn][d]*W[o][d]
// 128n x 128o tile, XOR-swizzled LDS, 8x8 micro-tile, W streamed one float4
// at a time in the inner loop (keeps live VGPRs ~110).
// HISTORY: R5-R7 register-resident-W designs all spilled or scalar-stalled
// (87/74/118 us). This LDS version is the known-best (~25-40 us).
// R5 lesson: outer loop `unroll 1` is safe ONLY because acc indices stay
// static within the unrolled inner loops.
// ---------------------------------------------------------------------------
__global__ __launch_bounds__(256) void lin_kernel(const float* __restrict__ x,
                                                  const float* __restrict__ W,
                                                  float* __restrict__ h) {
    __shared__ float Ws[128 * 64];
    __shared__ float Xs[128 * 64];
    const int tid = threadIdx.x;
    const int nblk = blockIdx.x >> 1;
    const int o0 = (blockIdx.x & 1) * 128;
    const int gn0 = nblk * 128;

#pragma unroll
    for (int q = 0; q < 8; ++q) {
        int flat = q * 256 + tid;
        int row = flat >> 4, d4 = flat & 15;
        float4 v = *(const float4*)(W + (size_t)(o0 + row) * 64 + d4 * 4);
        *(float4*)(Ws + row * 64 + ((d4 ^ ((row >> 3) & 7)) << 2)) = v;
    }
#pragma unroll
    for (int q = 0; q < 8; ++q) {
        int flat = q * 256 + tid;
        int row = flat >> 4, d4 = flat & 15;
        float4 v = *(const float4*)(x + (size_t)(gn0 + row) * 64 + d4 * 4);
        *(float4*)(Xs + row * 64 + ((d4 ^ (row & 7)) << 2)) = v;
    }
    __syncthreads();

    const int og = tid >> 4;
    const int ng = tid & 15;
    const int wsw = og & 7;
    const int xsw = ng & 7;
    float acc[8][8];
#pragma unroll
    for (int k = 0; k < 8; ++k)
#pragma unroll
        for (int j = 0; j < 8; ++j) acc[k][j] = 0.f;

#pragma unroll 1
    for (int d4 = 0; d4 < 16; ++d4) {
        float4 x4[8];
#pragma unroll
        for (int j = 0; j < 8; ++j)
            x4[j] = *(const float4*)(Xs + (ng + 16 * j) * 64 + ((d4 ^ xsw) << 2));
#pragma unroll
        for (int k = 0; k < 8; ++k) {
            float4 w = *(const float4*)(Ws + (og * 8 + k) * 64 + ((d4 ^ wsw) << 2));
#pragma unroll
            for (int j = 0; j < 8; ++j)
                acc[k][j] += w.x * x4[j].x + w.y * x4[j].y +
                             w.z * x4[j].z + w.w * x4[j].w;
        }
    }

#pragma unroll
    for (int j = 0; j < 8; ++j) {
        int gn = gn0 + ng + 16 * j;
        float* dst = h + (size_t)gn * 256 + o0 + og * 8;
        *(float4*)(dst) = make_float4(acc[0][j], acc[1][j], acc[2][j], acc[3][j]);
        *(float4*)(dst + 4) = make_float4(acc[4][j], acc[5][j], acc[6][j], acc[7][j]);
    }
}

// ---------------------------------------------------------------------------
// Kernel B1: attn_prep v2 — per (b,head). Shuffle-based bitonic sort (2
// consecutive elements/thread: j=1 in-reg, j<=64 shfl_xor, j in {128,256} via
// LDS -> only 3 barrier-stages vs 45). Wave-shfl scans for z1suf/z2pre.
// ---------------------------------------------------------------------------
__global__ __launch_bounds__(256) void attn_prep(const float* __restrict__ h,
                                                 const float* __restrict__ att_src,
                                                 const float* __restrict__ att_dst,
                                                 int* __restrict__ g_sidx,
                                                 float* __restrict__ g_E1,
                                                 float* __restrict__ g_E2,
                                                 float* __restrict__ g_aZ,
                                                 float* __restrict__ g_bZ,
                                                 int* __restrict__ g_k) {
    const int bh = blockIdx.x;
    const int b = bh >> 2;
    const int head = bh & 3;
    const int t = threadIdx.x;
    const int lane = t & 63;
    const int wid = t >> 6;

    __shared__ float att_s[64], att_d[64];
    __shared__ float s_val[512];
    __shared__ int   s_idxE[512];
    __shared__ float dArr[512];
    __shared__ float z1suf[513], z2pre[513];
    __shared__ float wred[8];

    if (t < 64) att_s[t] = att_src[head * 64 + t];
    else if (t < 128) att_d[t - 64] = att_dst[head * 64 + (t - 64)];
    __syncthreads();

    for (int rr = 0; rr < 2; ++rr) {
        int j = t + rr * 256;
        const float* hrow = h + ((size_t)(b * 512 + j) * 4 + head) * 64;
        float as = 0.f, ad = 0.f;
#pragma unroll
        for (int d4 = 0; d4 < 16; ++d4) {
            float4 hv = *(const float4*)(hrow + d4 * 4);
            float4 sv = *(const float4*)(att_s + d4 * 4);
            float4 dv = *(const float4*)(att_d + d4 * 4);
            as += hv.x * sv.x + hv.y * sv.y + hv.z * sv.z + hv.w * sv.w;
            ad += hv.x * dv.x + hv.y * dv.y + hv.z * dv.z + hv.w * dv.w;
        }
        s_val[j] = as; dArr[j] = ad;
    }
    __syncthreads();

    // Bitonic sort ascending; thread t holds positions 2t, 2t+1.
    float v0 = s_val[2 * t], v1 = s_val[2 * t + 1];
    int id0 = 2 * t, id1 = 2 * t + 1;
    for (int k = 2; k <= 512; k <<= 1) {
        for (int j = k >> 1; j >= 1; j >>= 1) {
            bool asc = ((t & (k >> 1)) == 0);
            if (j == 1) {
                bool sw = asc ? (v0 > v1) : (v0 < v1);
                if (sw) { float tv = v0; v0 = v1; v1 = tv; int ti = id0; id0 = id1; id1 = ti; }
            } else if (j <= 64) {
                int m = j >> 1;
                float w0 = __shfl_xor(v0, m, 64);
                int  wi0 = __shfl_xor(id0, m, 64);
                float w1 = __shfl_xor(v1, m, 64);
                int  wi1 = __shfl_xor(id1, m, 64);
                bool low = ((t & m) == 0);
                bool wantmin = (low == asc);
                if (wantmin ? (w0 < v0) : (w0 > v0)) { v0 = w0; id0 = wi0; }
                if (wantmin ? (w1 < v1) : (w1 > v1)) { v1 = w1; id1 = wi1; }
            } else {
                int m = j >> 1;
                s_val[2 * t] = v0; s_val[2 * t + 1] = v1;
                s_idxE[2 * t] = id0; s_idxE[2 * t + 1] = id1;
                __syncthreads();
                int tp = t ^ m;
                float w0 = s_val[2 * tp], w1 = s_val[2 * tp + 1];
                int wi0 = s_idxE[2 * tp], wi1 = s_idxE[2 * tp + 1];
                bool low = ((t & m) == 0);
                bool wantmin = (low == asc);
                if (wantmin ? (w0 < v0) : (w0 > v0)) { v0 = w0; id0 = wi0; }
                if (wantmin ? (w1 < v1) : (w1 > v1)) { v1 = w1; id1 = wi1; }
                __syncthreads();
            }
        }
    }

    s_val[2 * t] = v0; s_val[2 * t + 1] = v1;
    __syncthreads();
    const float M = s_val[511];
    float e1_0 = __expf(v0 - M), e1_1 = __expf(v1 - M);
    float e2_0 = __expf(0.2f * (v0 - M)), e2_1 = __expf(0.2f * (v1 - M));
    *(float2*)(g_E1 + bh * 512 + 2 * t) = make_float2(e1_0, e1_1);
    *(float2*)(g_E2 + bh * 512 + 2 * t) = make_float2(e2_0, e2_1);
    *(int2*)(g_sidx + bh * 512 + 2 * t) = make_int2(id0, id1);

    float S1 = e1_0 + e1_1, S2 = e2_0 + e2_1;
    float i1 = S1, i2 = S2;
    for (int off = 1; off < 64; off <<= 1) {
        float u1 = __shfl_up(i1, off, 64);
        float u2 = __shfl_up(i2, off, 64);
        if (lane >= off) { i1 += u1; i2 += u2; }
    }
    if (lane == 63) { wred[wid] = i1; wred[4 + wid] = i2; }
    __syncthreads();
    float off1 = 0.f, off2 = 0.f;
    for (int w = 0; w < wid; ++w) { off1 += wred[w]; off2 += wred[4 + w]; }
    const float T1 = wred[0] + wred[1] + wred[2] + wred[3];
    const float T2 = wred[4] + wred[5] + wred[6] + wred[7];
    float pre1 = off1 + i1 - S1;
    float pre2 = off2 + i2 - S2;
    z1suf[2 * t] = T1 - pre1;
    z1suf[2 * t + 1] = T1 - pre1 - e1_0;
    z2pre[2 * t] = pre2;
    z2pre[2 * t + 1] = pre2 + e2_0;
    if (t == 0) { z1suf[512] = 0.f; z2pre[512] = T2; }
    __syncthreads();

    for (int rr = 0; rr < 2; ++rr) {
        int i = t + rr * 256;
        float d = dArr[i];
        int lo = 0, hi = 512;
        while (lo < hi) {
            int mid = (lo + hi) >> 1;
            if (d + s_val[mid] >= 0.f) hi = mid; else lo = mid + 1;
        }
        int k = lo;
        float g = d + M;
        float G = (g >= 0.f) ? g : 0.2f * g;
        float al = __expf(g - G);
        float be = __expf(0.2f * g - G);
        float Z = al * z1suf[k] + be * z2pre[k];
        float inv = 1.0f / Z;
        g_aZ[bh * 512 + i] = al * inv;
        g_bZ[bh * 512 + i] = be * inv;
        g_k[bh * 512 + i]  = k;
    }
}

// ---------------------------------------------------------------------------
// Kernel B2: attn_agg v2 — 16 channels/block (grid 1024). 64-B aligned h
// gather held in registers; ONE 33-KB LDS table used twice. XCD swizzle:
// blockIdx = q*64 + b so all 16 blocks of a batch share an XCD.
// yH aliases h: all h reads (phase 0) precede yH writes (end), block-local.
// ---------------------------------------------------------------------------
#define APW 516
__global__ __launch_bounds__(256) void attn_agg(const float* __restrict__ h,
                                                const int* __restrict__ g_sidx,
                                                const float* __restrict__ g_E1,
                                                const float* __restrict__ g_E2,
                                                const float* __restrict__ g_aZ,
                                                const float* __restrict__ g_bZ,
                                                const int* __restrict__ g_k,
                                                float* __restrict__ yH) {
    const int b = blockIdx.x & 63;
    const int q = blockIdx.x >> 6;
    const int head = q >> 2;
    const int cg = q & 3;
    const int bh = b * 4 + head;
    const int c0 = cg * 16;
    const int t = threadIdx.x;

    __shared__ float A[16 * APW];
    __shared__ float segs[16 * 17];
    __shared__ float tot[16];
    __shared__ int   kA[512];
    __shared__ float aZs[512], bZs[512];

    float e1r[2], e2r[2], hv[2][16];
    for (int rr = 0; rr < 2; ++rr) {
        int r = t + rr * 256;
        int j = g_sidx[bh * 512 + r];
        e1r[rr] = g_E1[bh * 512 + r];
        e2r[rr] = g_E2[bh * 512 + r];
        kA[r]  = g_k[bh * 512 + r];
        aZs[r] = g_aZ[bh * 512 + r];
        bZs[r] = g_bZ[bh * 512 + r];
        const float* hp = h + ((size_t)(b * 512 + j) * 4 + head) * 64 + c0;
#pragma unroll
        for (int q4 = 0; q4 < 4; ++q4) {
            float4 v = *(const float4*)(hp + q4 * 4);
            hv[rr][q4 * 4 + 0] = v.x; hv[rr][q4 * 4 + 1] = v.y;
            hv[rr][q4 * 4 + 2] = v.z; hv[rr][q4 * 4 + 3] = v.w;
        }
    }
    __syncthreads();

    // ---- Pass A: suffix table of E1*h ----
    for (int rr = 0; rr < 2; ++rr) {
        int r = t + rr * 256;
#pragma unroll
        for (int c = 0; c < 16; ++c) A[c * APW + r] = e1r[rr] * hv[rr][c];
    }
    __syncthreads();
    {
        int ch = t & 15, seg = t >> 4;
        float* base = A + ch * APW + seg * 32;
        float v[32];
#pragma unroll
        for (int q4 = 0; q4 < 8; ++q4) {
            float4 a = *(const float4*)(base + q4 * 4);
            v[q4 * 4] = a.x; v[q4 * 4 + 1] = a.y; v[q4 * 4 + 2] = a.z; v[q4 * 4 + 3] = a.w;
        }
        float s = 0.f;
#pragma unroll
        for (int i = 0; i < 32; ++i) s += v[i];
        segs[ch * 17 + seg] = s;
        __syncthreads();
        float suf = 0.f;
        for (int s2 = seg + 1; s2 < 16; ++s2) suf += segs[ch * 17 + s2];
        float run = suf;
#pragma unroll
        for (int i = 31; i >= 0; --i) { run += v[i]; v[i] = run; }
#pragma unroll
        for (int q4 = 0; q4 < 8; ++q4)
            *(float4*)(base + q4 * 4) = make_float4(v[q4 * 4], v[q4 * 4 + 1], v[q4 * 4 + 2], v[q4 * 4 + 3]);
    }
    __syncthreads();
    float part[32];
    {
        int cl = t & 15, ibase = t >> 4;
#pragma unroll
        for (int p = 0; p < 32; ++p) {
            int i = p * 16 + ibase;
            int k = kA[i];
            float S1v = (k < 512) ? A[cl * APW + k] : 0.f;
            part[p] = aZs[i] * S1v;
        }
    }
    __syncthreads();

    // ---- Pass B: exclusive-prefix table of E2*h ----
    for (int rr = 0; rr < 2; ++rr) {
        int r = t + rr * 256;
#pragma unroll
        for (int c = 0; c < 16; ++c) A[c * APW + r] = e2r[rr] * hv[rr][c];
    }
    __syncthreads();
    {
        int ch = t & 15, seg = t >> 4;
        float* base = A + ch * APW + seg * 32;
        float v[32];
#pragma unroll
        for (int q4 = 0; q4 < 8; ++q4) {
            float4 a = *(const float4*)(base + q4 * 4);
            v[q4 * 4] = a.x; v[q4 * 4 + 1] = a.y; v[q4 * 4 + 2] = a.z; v[q4 * 4 + 3] = a.w;
        }
        float s = 0.f;
#pragma unroll
        for (int i = 0; i < 32; ++i) s += v[i];
        segs[ch * 17 + seg] = s;
        __syncthreads();
        float pre = 0.f;
        for (int s2 = 0; s2 < seg; ++s2) pre += segs[ch * 17 + s2];
        float run2 = pre;
#pragma unroll
        for (int i = 0; i < 32; ++i) { float tv = v[i]; v[i] = run2; run2 += tv; }
#pragma unroll
        for (int q4 = 0; q4 < 8; ++q4)
            *(float4*)(base + q4 * 4) = make_float4(v[q4 * 4], v[q4 * 4 + 1], v[q4 * 4 + 2], v[q4 * 4 + 3]);
        if (seg == 15) tot[ch] = run2;
    }
    __syncthreads();
    {
        int cl = t & 15, ibase = t >> 4;
#pragma unroll
        for (int p = 0; p < 32; ++p) {
            int i = p * 16 + ibase;
            int k = kA[i];
            float P2 = (k < 512) ? A[cl * APW + k] : tot[cl];
            float val = part[p] + bZs[i] * P2;
            yH[((size_t)(b * 512 + i) * 4 + head) * 64 + c0 + cl] = val;
        }
    }
}

// ---------------------------------------------------------------------------
// Kernel C: x[bn][c] = relu( mean_h yH[bn][h][c] + bias[c] )
// ---------------------------------------------------------------------------
__global__ __launch_bounds__(256) void finalize_kernel(const float* __restrict__ yH,
                                                       const float* __restrict__ bias,
                                                       float* __restrict__ x) {
    int idx = blockIdx.x * 256 + threadIdx.x;
    int bn = idx >> 4, c4 = idx & 15;
    const float* yp = yH + (size_t)bn * 256 + c4 * 4;
    float4 v0 = *(const float4*)(yp);
    float4 v1 = *(const float4*)(yp + 64);
    float4 v2 = *(const float4*)(yp + 128);
    float4 v3 = *(const float4*)(yp + 192);
    float4 bs = *(const float4*)(bias + c4 * 4);
    float4 o;
    o.x = fmaxf(0.25f * (v0.x + v1.x + v2.x + v3.x) + bs.x, 0.f);
    o.y = fmaxf(0.25f * (v0.y + v1.y + v2.y + v3.y) + bs.y, 0.f);
    o.z = fmaxf(0.25f * (v0.z + v1.z + v2.z + v3.z) + bs.z, 0.f);
    o.w = fmaxf(0.25f * (v0.w + v1.w + v2.w + v3.w) + bs.w, 0.f);
    *(float4*)(x + (size_t)bn * 64 + c4 * 4) = o;
}

// ---------------------------------------------------------------------------
// Kernel D: out[b][d] = (mean_n x[b][n][:]) . readout_w[d][:] + readout_b[d]
// ---------------------------------------------------------------------------
__global__ __launch_bounds__(256) void readout_kernel(const float* __restrict__ x,
                                                      const float* __restrict__ rw,
                                                      const float* __restrict__ rb,
                                                      float* __restrict__ out) {
    __shared__ float red[4][64];
    __shared__ float pooled[64];
    int b = blockIdx.x, t = threadIdx.x;
    int c = t & 63, q = t >> 6;
    float acc = 0.f;
    for (int n = q; n < 512; n += 4) acc += x[((size_t)b * 512 + n) * 64 + c];
    red[q][c] = acc;
    __syncthreads();
    if (t < 64) pooled[t] = (red[0][t] + red[1][t] + red[2][t] + red[3][t]) * (1.0f / 512.0f);
    __syncthreads();
    if (t < 64) {
        float a = rb[t];
        for (int cc = 0; cc < 64; ++cc) a += pooled[cc] * rw[t * 64 + cc];
        out[b * 64 + t] = a;
    }
}

extern "C" void kernel_launch(void* const* d_in, const int* in_sizes, int n_in,
                              void* d_out, int out_size, void* d_ws, size_t ws_size,
                              hipStream_t stream) {
    const float* emb       = (const float*)d_in[0];
    const float* lin_w     = (const float*)d_in[1];
    const float* att_src   = (const float*)d_in[2];
    const float* att_dst   = (const float*)d_in[3];
    const float* conv_b    = (const float*)d_in[4];
    const float* readout_w = (const float*)d_in[5];
    const float* readout_b = (const float*)d_in[6];
    float* out = (float*)d_out;

    float* ws   = (float*)d_ws;
    float* xbuf = ws;                  // 2,097,152 floats (8 MB)
    float* hbuf = ws + 2097152;        // 8,388,608 floats (32 MB)

    int*   g_sidx = (int*)xbuf;
    float* g_E1   = xbuf + 131072;
    float* g_E2   = xbuf + 262144;
    float* g_aZ   = xbuf + 393216;
    float* g_bZ   = xbuf + 524288;
    int*   g_k    = (int*)(xbuf + 655360);

    for (int l = 0; l < 3; ++l) {
        const float* xin = (l == 0) ? emb : xbuf;
        lin_kernel<<<512, 256, 0, stream>>>(xin, lin_w + (size_t)l * 16384, hbuf);
        attn_prep<<<256, 256, 0, stream>>>(hbuf, att_src + l * 256, att_dst + l * 256,
                                           g_sidx, g_E1, g_E2, g_aZ, g_bZ, g_k);
        attn_agg<<<1024, 256, 0, stream>>>(hbuf, g_sidx, g_E1, g_E2, g_aZ, g_bZ, g_k, hbuf);
        finalize_kernel<<<2048, 256, 0, stream>>>(hbuf, conv_b + l * 64, xbuf);
    }
    readout_kernel<<<64, 256, 0, stream>>>(xbuf, readout_w, readout_b, out);
}

// Round 9
// 297.187 us; speedup vs baseline: 1.5886x; 1.0823x over previous
//
#include <hip/hip_runtime.h>
#include <math.h>

// Problem constants (fixed by reference): B=64, N=512, D=64, H=4, C=64, L=3
// Workspace layout (floats):
//   xbuf [0 .. 2097152)        : layer activations x (B*N*64) = 8 MB
//     -- prep metadata (3 MB) overlaid at FRONT of xbuf between lin (reads x)
//        and finalize (rewrites x); stream order makes it safe.
//   hbuf [2097152 .. 10485760) : h (B*N*H*C) = 32 MB; yH aliases h.

using short8  = __attribute__((ext_vector_type(8))) short;
using floatx4 = __attribute__((ext_vector_type(4))) float;

__device__ inline unsigned short f2bf(float f) {
    union { float f; unsigned u; } v; v.f = f;
    unsigned u = v.u + 0x7FFFu + ((v.u >> 16) & 1u);   // round-to-nearest-even
    return (unsigned short)(u >> 16);
}
__device__ inline float bf2f(unsigned short s) {
    union { float f; unsigned u; } v; v.u = ((unsigned)s) << 16;
    return v.f;
}

// ---------------------------------------------------------------------------
// Kernel A v6 (MFMA split-bf16): h = x @ W^T via 3 bf16 MFMA products.
// x = xh+xl, W = wh+wl (bf16 hi + bf16 residual); h = xh*wh + xh*wl + xl*wh
// (dropped xl*wl ~ |x||w|*2^-18 -> ~1e-5 abs error, threshold 1.4e-4).
// Block: 4 waves, tile 16 rows x 64 cols; each wave one 16x16 MFMA tile per
// 16-col group. K=64 -> 2 mfma per product = 6 mfma/wave. LDS 23 KB,
// grid 8192 -> ~6 blocks/CU. HBM floor ~7 us (8 MB x read + 32 MB h write).
// Layouts [m89/m91/m120]: A[m=lane&15][k=quad*8+j], B[k=quad*8+j][n=lane&15],
// C col=lane&15, row=quad*4+reg.
// HISTORY: fp32 vector-ALU versions: LDS-tile 45us (latency-bound), three
// register/scalar redesigns failed (spills / K$ thrash, R5-R7).
// ---------------------------------------------------------------------------
__global__ __launch_bounds__(256) void lin_kernel(const float* __restrict__ x,
                                                  const float* __restrict__ W,
                                                  float* __restrict__ h) {
    __shared__ unsigned short XH[16 * 72], XL[16 * 72];
    __shared__ unsigned short WH[64 * 72], WL[64 * 72];

    const int t = threadIdx.x;
    const int ct = blockIdx.x & 3;        // col tile (low bits: L2 W sharing)
    const int rt = blockIdx.x >> 2;       // row tile 0..2047
    const int r0 = rt * 16;
    const int c0 = ct * 64;

    // Stage x tile: 16 rows x 64 -> bf16 hi/lo. Thread t: one float4.
    {
        int row = t >> 4, d4 = t & 15;
        float4 v = *(const float4*)(x + (size_t)(r0 + row) * 64 + d4 * 4);
        unsigned short h0 = f2bf(v.x), h1 = f2bf(v.y), h2 = f2bf(v.z), h3 = f2bf(v.w);
        ushort4 hi = make_ushort4(h0, h1, h2, h3);
        ushort4 lo = make_ushort4(f2bf(v.x - bf2f(h0)), f2bf(v.y - bf2f(h1)),
                                  f2bf(v.z - bf2f(h2)), f2bf(v.w - bf2f(h3)));
        *(ushort4*)&XH[row * 72 + d4 * 4] = hi;
        *(ushort4*)&XL[row * 72 + d4 * 4] = lo;
    }
    // Stage W tile: 64 cols x 64 -> bf16 hi/lo. Thread t: four float4s.
#pragma unroll
    for (int q = 0; q < 4; ++q) {
        int f = q * 256 + t;
        int wrow = f >> 4, d4 = f & 15;
        float4 v = *(const float4*)(W + (size_t)(c0 + wrow) * 64 + d4 * 4);
        unsigned short h0 = f2bf(v.x), h1 = f2bf(v.y), h2 = f2bf(v.z), h3 = f2bf(v.w);
        ushort4 hi = make_ushort4(h0, h1, h2, h3);
        ushort4 lo = make_ushort4(f2bf(v.x - bf2f(h0)), f2bf(v.y - bf2f(h1)),
                                  f2bf(v.z - bf2f(h2)), f2bf(v.w - bf2f(h3)));
        *(ushort4*)&WH[wrow * 72 + d4 * 4] = hi;
        *(ushort4*)&WL[wrow * 72 + d4 * 4] = lo;
    }
    __syncthreads();

    const int lane = t & 63, wv = t >> 6;
    const int mrow = lane & 15, quad = lane >> 4;

    short8 ah[2], al[2], bh[2], bl[2];
#pragma unroll
    for (int kk = 0; kk < 2; ++kk) {
        int ko = kk * 32 + quad * 8;
        ah[kk] = *(const short8*)&XH[mrow * 72 + ko];
        al[kk] = *(const short8*)&XL[mrow * 72 + ko];
        bh[kk] = *(const short8*)&WH[(wv * 16 + mrow) * 72 + ko];
        bl[kk] = *(const short8*)&WL[(wv * 16 + mrow) * 72 + ko];
    }

    floatx4 acc = {0.f, 0.f, 0.f, 0.f};
    acc = __builtin_amdgcn_mfma_f32_16x16x32_bf16(ah[0], bh[0], acc, 0, 0, 0);
    acc = __builtin_amdgcn_mfma_f32_16x16x32_bf16(ah[1], bh[1], acc, 0, 0, 0);
    acc = __builtin_amdgcn_mfma_f32_16x16x32_bf16(ah[0], bl[0], acc, 0, 0, 0);
    acc = __builtin_amdgcn_mfma_f32_16x16x32_bf16(ah[1], bl[1], acc, 0, 0, 0);
    acc = __builtin_amdgcn_mfma_f32_16x16x32_bf16(al[0], bh[0], acc, 0, 0, 0);
    acc = __builtin_amdgcn_mfma_f32_16x16x32_bf16(al[1], bh[1], acc, 0, 0, 0);

    // C layout: col = lane&15, row = quad*4 + reg
    const int colo = c0 + wv * 16 + mrow;
#pragma unroll
    for (int reg = 0; reg < 4; ++reg)
        h[(size_t)(r0 + quad * 4 + reg) * 256 + colo] = acc[reg];
}

// ---------------------------------------------------------------------------
// Kernel B1: attn_prep v2 — per (b,head). Shuffle-based bitonic sort (2
// consecutive elements/thread: j=1 in-reg, j<=64 shfl_xor, j in {128,256} via
// LDS -> only 3 barrier-stages vs 45). Wave-shfl scans for z1suf/z2pre.
// ---------------------------------------------------------------------------
__global__ __launch_bounds__(256) void attn_prep(const float* __restrict__ h,
                                                 const float* __restrict__ att_src,
                                                 const float* __restrict__ att_dst,
                                                 int* __restrict__ g_sidx,
                                                 float* __restrict__ g_E1,
                                                 float* __restrict__ g_E2,
                                                 float* __restrict__ g_aZ,
                                                 float* __restrict__ g_bZ,
                                                 int* __restrict__ g_k) {
    const int bh = blockIdx.x;
    const int b = bh >> 2;
    const int head = bh & 3;
    const int t = threadIdx.x;
    const int lane = t & 63;
    const int wid = t >> 6;

    __shared__ float att_s[64], att_d[64];
    __shared__ float s_val[512];
    __shared__ int   s_idxE[512];
    __shared__ float dArr[512];
    __shared__ float z1suf[513], z2pre[513];
    __shared__ float wred[8];

    if (t < 64) att_s[t] = att_src[head * 64 + t];
    else if (t < 128) att_d[t - 64] = att_dst[head * 64 + (t - 64)];
    __syncthreads();

    for (int rr = 0; rr < 2; ++rr) {
        int j = t + rr * 256;
        const float* hrow = h + ((size_t)(b * 512 + j) * 4 + head) * 64;
        float as = 0.f, ad = 0.f;
#pragma unroll
        for (int d4 = 0; d4 < 16; ++d4) {
            float4 hv = *(const float4*)(hrow + d4 * 4);
            float4 sv = *(const float4*)(att_s + d4 * 4);
            float4 dv = *(const float4*)(att_d + d4 * 4);
            as += hv.x * sv.x + hv.y * sv.y + hv.z * sv.z + hv.w * sv.w;
            ad += hv.x * dv.x + hv.y * dv.y + hv.z * dv.z + hv.w * dv.w;
        }
        s_val[j] = as; dArr[j] = ad;
    }
    __syncthreads();

    // Bitonic sort ascending; thread t holds positions 2t, 2t+1.
    float v0 = s_val[2 * t], v1 = s_val[2 * t + 1];
    int id0 = 2 * t, id1 = 2 * t + 1;
    for (int k = 2; k <= 512; k <<= 1) {
        for (int j = k >> 1; j >= 1; j >>= 1) {
            bool asc = ((t & (k >> 1)) == 0);
            if (j == 1) {
                bool sw = asc ? (v0 > v1) : (v0 < v1);
                if (sw) { float tv = v0; v0 = v1; v1 = tv; int ti = id0; id0 = id1; id1 = ti; }
            } else if (j <= 64) {
                int m = j >> 1;
                float w0 = __shfl_xor(v0, m, 64);
                int  wi0 = __shfl_xor(id0, m, 64);
                float w1 = __shfl_xor(v1, m, 64);
                int  wi1 = __shfl_xor(id1, m, 64);
                bool low = ((t & m) == 0);
                bool wantmin = (low == asc);
                if (wantmin ? (w0 < v0) : (w0 > v0)) { v0 = w0; id0 = wi0; }
                if (wantmin ? (w1 < v1) : (w1 > v1)) { v1 = w1; id1 = wi1; }
            } else {
                int m = j >> 1;
                s_val[2 * t] = v0; s_val[2 * t + 1] = v1;
                s_idxE[2 * t] = id0; s_idxE[2 * t + 1] = id1;
                __syncthreads();
                int tp = t ^ m;
                float w0 = s_val[2 * tp], w1 = s_val[2 * tp + 1];
                int wi0 = s_idxE[2 * tp], wi1 = s_idxE[2 * tp + 1];
                bool low = ((t & m) == 0);
                bool wantmin = (low == asc);
                if (wantmin ? (w0 < v0) : (w0 > v0)) { v0 = w0; id0 = wi0; }
                if (wantmin ? (w1 < v1) : (w1 > v1)) { v1 = w1; id1 = wi1; }
                __syncthreads();
            }
        }
    }

    s_val[2 * t] = v0; s_val[2 * t + 1] = v1;
    __syncthreads();
    const float M = s_val[511];
    float e1_0 = __expf(v0 - M), e1_1 = __expf(v1 - M);
    float e2_0 = __expf(0.2f * (v0 - M)), e2_1 = __expf(0.2f * (v1 - M));
    *(float2*)(g_E1 + bh * 512 + 2 * t) = make_float2(e1_0, e1_1);
    *(float2*)(g_E2 + bh * 512 + 2 * t) = make_float2(e2_0, e2_1);
    *(int2*)(g_sidx + bh * 512 + 2 * t) = make_int2(id0, id1);

    float S1 = e1_0 + e1_1, S2 = e2_0 + e2_1;
    float i1 = S1, i2 = S2;
    for (int off = 1; off < 64; off <<= 1) {
        float u1 = __shfl_up(i1, off, 64);
        float u2 = __shfl_up(i2, off, 64);
        if (lane >= off) { i1 += u1; i2 += u2; }
    }
    if (lane == 63) { wred[wid] = i1; wred[4 + wid] = i2; }
    __syncthreads();
    float off1 = 0.f, off2 = 0.f;
    for (int w = 0; w < wid; ++w) { off1 += wred[w]; off2 += wred[4 + w]; }
    const float T1 = wred[0] + wred[1] + wred[2] + wred[3];
    const float T2 = wred[4] + wred[5] + wred[6] + wred[7];
    float pre1 = off1 + i1 - S1;
    float pre2 = off2 + i2 - S2;
    z1suf[2 * t] = T1 - pre1;
    z1suf[2 * t + 1] = T1 - pre1 - e1_0;
    z2pre[2 * t] = pre2;
    z2pre[2 * t + 1] = pre2 + e2_0;
    if (t == 0) { z1suf[512] = 0.f; z2pre[512] = T2; }
    __syncthreads();

    for (int rr = 0; rr < 2; ++rr) {
        int i = t + rr * 256;
        float d = dArr[i];
        int lo = 0, hi = 512;
        while (lo < hi) {
            int mid = (lo + hi) >> 1;
            if (d + s_val[mid] >= 0.f) hi = mid; else lo = mid + 1;
        }
        int k = lo;
        float g = d + M;
        float G = (g >= 0.f) ? g : 0.2f * g;
        float al = __expf(g - G);
        float be = __expf(0.2f * g - G);
        float Z = al * z1suf[k] + be * z2pre[k];
        float inv = 1.0f / Z;
        g_aZ[bh * 512 + i] = al * inv;
        g_bZ[bh * 512 + i] = be * inv;
        g_k[bh * 512 + i]  = k;
    }
}

// ---------------------------------------------------------------------------
// Kernel B2: attn_agg v2 — 16 channels/block (grid 1024). 64-B aligned h
// gather held in registers; ONE 33-KB LDS table used twice. XCD swizzle:
// blockIdx = q*64 + b so all 16 blocks of a batch share an XCD.
// yH aliases h: all h reads (phase 0) precede yH writes (end), block-local.
// ---------------------------------------------------------------------------
#define APW 516
__global__ __launch_bounds__(256) void attn_agg(const float* __restrict__ h,
                                                const int* __restrict__ g_sidx,
                                                const float* __restrict__ g_E1,
                                                const float* __restrict__ g_E2,
                                                const float* __restrict__ g_aZ,
                                                const float* __restrict__ g_bZ,
                                                const int* __restrict__ g_k,
                                                float* __restrict__ yH) {
    const int b = blockIdx.x & 63;
    const int q = blockIdx.x >> 6;
    const int head = q >> 2;
    const int cg = q & 3;
    const int bh = b * 4 + head;
    const int c0 = cg * 16;
    const int t = threadIdx.x;

    __shared__ float A[16 * APW];
    __shared__ float segs[16 * 17];
    __shared__ float tot[16];
    __shared__ int   kA[512];
    __shared__ float aZs[512], bZs[512];

    float e1r[2], e2r[2], hv[2][16];
    for (int rr = 0; rr < 2; ++rr) {
        int r = t + rr * 256;
        int j = g_sidx[bh * 512 + r];
        e1r[rr] = g_E1[bh * 512 + r];
        e2r[rr] = g_E2[bh * 512 + r];
        kA[r]  = g_k[bh * 512 + r];
        aZs[r] = g_aZ[bh * 512 + r];
        bZs[r] = g_bZ[bh * 512 + r];
        const float* hp = h + ((size_t)(b * 512 + j) * 4 + head) * 64 + c0;
#pragma unroll
        for (int q4 = 0; q4 < 4; ++q4) {
            float4 v = *(const float4*)(hp + q4 * 4);
            hv[rr][q4 * 4 + 0] = v.x; hv[rr][q4 * 4 + 1] = v.y;
            hv[rr][q4 * 4 + 2] = v.z; hv[rr][q4 * 4 + 3] = v.w;
        }
    }
    __syncthreads();

    // ---- Pass A: suffix table of E1*h ----
    for (int rr = 0; rr < 2; ++rr) {
        int r = t + rr * 256;
#pragma unroll
        for (int c = 0; c < 16; ++c) A[c * APW + r] = e1r[rr] * hv[rr][c];
    }
    __syncthreads();
    {
        int ch = t & 15, seg = t >> 4;
        float* base = A + ch * APW + seg * 32;
        float v[32];
#pragma unroll
        for (int q4 = 0; q4 < 8; ++q4) {
            float4 a = *(const float4*)(base + q4 * 4);
            v[q4 * 4] = a.x; v[q4 * 4 + 1] = a.y; v[q4 * 4 + 2] = a.z; v[q4 * 4 + 3] = a.w;
        }
        float s = 0.f;
#pragma unroll
        for (int i = 0; i < 32; ++i) s += v[i];
        segs[ch * 17 + seg] = s;
        __syncthreads();
        float suf = 0.f;
        for (int s2 = seg + 1; s2 < 16; ++s2) suf += segs[ch * 17 + s2];
        float run = suf;
#pragma unroll
        for (int i = 31; i >= 0; --i) { run += v[i]; v[i] = run; }
#pragma unroll
        for (int q4 = 0; q4 < 8; ++q4)
            *(float4*)(base + q4 * 4) = make_float4(v[q4 * 4], v[q4 * 4 + 1], v[q4 * 4 + 2], v[q4 * 4 + 3]);
    }
    __syncthreads();
    float part[32];
    {
        int cl = t & 15, ibase = t >> 4;
#pragma unroll
        for (int p = 0; p < 32; ++p) {
            int i = p * 16 + ibase;
            int k = kA[i];
            float S1v = (k < 512) ? A[cl * APW + k] : 0.f;
            part[p] = aZs[i] * S1v;
        }
    }
    __syncthreads();

    // ---- Pass B: exclusive-prefix table of E2*h ----
    for (int rr = 0; rr < 2; ++rr) {
        int r = t + rr * 256;
#pragma unroll
        for (int c = 0; c < 16; ++c) A[c * APW + r] = e2r[rr] * hv[rr][c];
    }
    __syncthreads();
    {
        int ch = t & 15, seg = t >> 4;
        float* base = A + ch * APW + seg * 32;
        float v[32];
#pragma unroll
        for (int q4 = 0; q4 < 8; ++q4) {
            float4 a = *(const float4*)(base + q4 * 4);
            v[q4 * 4] = a.x; v[q4 * 4 + 1] = a.y; v[q4 * 4 + 2] = a.z; v[q4 * 4 + 3] = a.w;
        }
        float s = 0.f;
#pragma unroll
        for (int i = 0; i < 32; ++i) s += v[i];
        segs[ch * 17 + seg] = s;
        __syncthreads();
        float pre = 0.f;
        for (int s2 = 0; s2 < seg; ++s2) pre += segs[ch * 17 + s2];
        float run2 = pre;
#pragma unroll
        for (int i = 0; i < 32; ++i) { float tv = v[i]; v[i] = run2; run2 += tv; }
#pragma unroll
        for (int q4 = 0; q4 < 8; ++q4)
            *(float4*)(base + q4 * 4) = make_float4(v[q4 * 4], v[q4 * 4 + 1], v[q4 * 4 + 2], v[q4 * 4 + 3]);
        if (seg == 15) tot[ch] = run2;
    }
    __syncthreads();
    {
        int cl = t & 15, ibase = t >> 4;
#pragma unroll
        for (int p = 0; p < 32; ++p) {
            int i = p * 16 + ibase;
            int k = kA[i];
            float P2 = (k < 512) ? A[cl * APW + k] : tot[cl];
            float val = part[p] + bZs[i] * P2;
            yH[((size_t)(b * 512 + i) * 4 + head) * 64 + c0 + cl] = val;
        }
    }
}

// ---------------------------------------------------------------------------
// Kernel C: x[bn][c] = relu( mean_h yH[bn][h][c] + bias[c] )
// ---------------------------------------------------------------------------
__global__ __launch_bounds__(256) void finalize_kernel(const float* __restrict__ yH,
                                                       const float* __restrict__ bias,
                                                       float* __restrict__ x) {
    int idx = blockIdx.x * 256 + threadIdx.x;
    int bn = idx >> 4, c4 = idx & 15;
    const float* yp = yH + (size_t)bn * 256 + c4 * 4;
    float4 v0 = *(const float4*)(yp);
    float4 v1 = *(const float4*)(yp + 64);
    float4 v2 = *(const float4*)(yp + 128);
    float4 v3 = *(const float4*)(yp + 192);
    float4 bs = *(const float4*)(bias + c4 * 4);
    float4 o;
    o.x = fmaxf(0.25f * (v0.x + v1.x + v2.x + v3.x) + bs.x, 0.f);
    o.y = fmaxf(0.25f * (v0.y + v1.y + v2.y + v3.y) + bs.y, 0.f);
    o.z = fmaxf(0.25f * (v0.z + v1.z + v2.z + v3.z) + bs.z, 0.f);
    o.w = fmaxf(0.25f * (v0.w + v1.w + v2.w + v3.w) + bs.w, 0.f);
    *(float4*)(x + (size_t)bn * 64 + c4 * 4) = o;
}

// ---------------------------------------------------------------------------
// Kernel D: out[b][d] = (mean_n x[b][n][:]) . readout_w[d][:] + readout_b[d]
// ---------------------------------------------------------------------------
__global__ __launch_bounds__(256) void readout_kernel(const float* __restrict__ x,
                                                      const float* __restrict__ rw,
                                                      const float* __restrict__ rb,
                                                      float* __restrict__ out) {
    __shared__ float red[4][64];
    __shared__ float pooled[64];
    int b = blockIdx.x, t = threadIdx.x;
    int c = t & 63, q = t >> 6;
    float acc = 0.f;
    for (int n = q; n < 512; n += 4) acc += x[((size_t)b * 512 + n) * 64 + c];
    red[q][c] = acc;
    __syncthreads();
    if (t < 64) pooled[t] = (red[0][t] + red[1][t] + red[2][t] + red[3][t]) * (1.0f / 512.0f);
    __syncthreads();
    if (t < 64) {
        float a = rb[t];
        for (int cc = 0; cc < 64; ++cc) a += pooled[cc] * rw[t * 64 + cc];
        out[b * 64 + t] = a;
    }
}

extern "C" void kernel_launch(void* const* d_in, const int* in_sizes, int n_in,
                              void* d_out, int out_size, void* d_ws, size_t ws_size,
                              hipStream_t stream) {
    const float* emb       = (const float*)d_in[0];
    const float* lin_w     = (const float*)d_in[1];
    const float* att_src   = (const float*)d_in[2];
    const float* att_dst   = (const float*)d_in[3];
    const float* conv_b    = (const float*)d_in[4];
    const float* readout_w = (const float*)d_in[5];
    const float* readout_b = (const float*)d_in[6];
    float* out = (float*)d_out;

    float* ws   = (float*)d_ws;
    float* xbuf = ws;                  // 2,097,152 floats (8 MB)
    float* hbuf = ws + 2097152;        // 8,388,608 floats (32 MB)

    int*   g_sidx = (int*)xbuf;
    float* g_E1   = xbuf + 131072;
    float* g_E2   = xbuf + 262144;
    float* g_aZ   = xbuf + 393216;
    float* g_bZ   = xbuf + 524288;
    int*   g_k    = (int*)(xbuf + 655360);

    for (int l = 0; l < 3; ++l) {
        const float* xin = (l == 0) ? emb : xbuf;
        lin_kernel<<<8192, 256, 0, stream>>>(xin, lin_w + (size_t)l * 16384, hbuf);
        attn_prep<<<256, 256, 0, stream>>>(hbuf, att_src + l * 256, att_dst + l * 256,
                                           g_sidx, g_E1, g_E2, g_aZ, g_bZ, g_k);
        attn_agg<<<1024, 256, 0, stream>>>(hbuf, g_sidx, g_E1, g_E2, g_aZ, g_bZ, g_k, hbuf);
        finalize_kernel<<<2048, 256, 0, stream>>>(hbuf, conv_b + l * 64, xbuf);
    }
    readout_kernel<<<64, 256, 0, stream>>>(xbuf, readout_w, readout_b, out);
}

// Round 10
// 289.204 us; speedup vs baseline: 1.6324x; 1.0276x over previous
//
#include <hip/hip_runtime.h>
#include <math.h>

// Problem constants (fixed by reference): B=64, N=512, D=64, H=4, C=64, L=3
// Workspace layout (floats), ws >= 256 MB (fill evidence: 262144 KB poison):
//   xbuf [0 .. 2097152)         : layer activations x (8 MB) — no overlays now
//   hbuf [2097152 .. 10485760)  : h (B*N*H*C) = 32 MB
//   meta [10485760 .. 11272192) : prep metadata (3 MB) — moved out of xbuf
//     because fused agg reads metadata WHILE writing x (R9 fusion).

using short8  = __attribute__((ext_vector_type(8))) short;
using floatx4 = __attribute__((ext_vector_type(4))) float;

__device__ inline unsigned short f2bf(float f) {
    union { float f; unsigned u; } v; v.f = f;
    unsigned u = v.u + 0x7FFFu + ((v.u >> 16) & 1u);   // round-to-nearest-even
    return (unsigned short)(u >> 16);
}
__device__ inline float bf2f(unsigned short s) {
    union { float f; unsigned u; } v; v.u = ((unsigned)s) << 16;
    return v.f;
}

// ---------------------------------------------------------------------------
// Kernel A v6 (MFMA split-bf16): h = x @ W^T via 3 bf16 MFMA products.
// h = xh*wh + xh*wl + xl*wh (dropped xl*wl ~ 1e-5 abs, threshold 1.4e-4).
// Verified R9: absmax unchanged vs fp32 path. 16x64 tile/block, grid 8192.
// ---------------------------------------------------------------------------
__global__ __launch_bounds__(256) void lin_kernel(const float* __restrict__ x,
                                                  const float* __restrict__ W,
                                                  float* __restrict__ h) {
    __shared__ unsigned short XH[16 * 72], XL[16 * 72];
    __shared__ unsigned short WH[64 * 72], WL[64 * 72];

    const int t = threadIdx.x;
    const int ct = blockIdx.x & 3;
    const int rt = blockIdx.x >> 2;
    const int r0 = rt * 16;
    const int c0 = ct * 64;

    {
        int row = t >> 4, d4 = t & 15;
        float4 v = *(const float4*)(x + (size_t)(r0 + row) * 64 + d4 * 4);
        unsigned short h0 = f2bf(v.x), h1 = f2bf(v.y), h2 = f2bf(v.z), h3 = f2bf(v.w);
        ushort4 hi = make_ushort4(h0, h1, h2, h3);
        ushort4 lo = make_ushort4(f2bf(v.x - bf2f(h0)), f2bf(v.y - bf2f(h1)),
                                  f2bf(v.z - bf2f(h2)), f2bf(v.w - bf2f(h3)));
        *(ushort4*)&XH[row * 72 + d4 * 4] = hi;
        *(ushort4*)&XL[row * 72 + d4 * 4] = lo;
    }
#pragma unroll
    for (int q = 0; q < 4; ++q) {
        int f = q * 256 + t;
        int wrow = f >> 4, d4 = f & 15;
        float4 v = *(const float4*)(W + (size_t)(c0 + wrow) * 64 + d4 * 4);
        unsigned short h0 = f2bf(v.x), h1 = f2bf(v.y), h2 = f2bf(v.z), h3 = f2bf(v.w);
        ushort4 hi = make_ushort4(h0, h1, h2, h3);
        ushort4 lo = make_ushort4(f2bf(v.x - bf2f(h0)), f2bf(v.y - bf2f(h1)),
                                  f2bf(v.z - bf2f(h2)), f2bf(v.w - bf2f(h3)));
        *(ushort4*)&WH[wrow * 72 + d4 * 4] = hi;
        *(ushort4*)&WL[wrow * 72 + d4 * 4] = lo;
    }
    __syncthreads();

    const int lane = t & 63, wv = t >> 6;
    const int mrow = lane & 15, quad = lane >> 4;

    short8 ah[2], al[2], bh[2], bl[2];
#pragma unroll
    for (int kk = 0; kk < 2; ++kk) {
        int ko = kk * 32 + quad * 8;
        ah[kk] = *(const short8*)&XH[mrow * 72 + ko];
        al[kk] = *(const short8*)&XL[mrow * 72 + ko];
        bh[kk] = *(const short8*)&WH[(wv * 16 + mrow) * 72 + ko];
        bl[kk] = *(const short8*)&WL[(wv * 16 + mrow) * 72 + ko];
    }

    floatx4 acc = {0.f, 0.f, 0.f, 0.f};
    acc = __builtin_amdgcn_mfma_f32_16x16x32_bf16(ah[0], bh[0], acc, 0, 0, 0);
    acc = __builtin_amdgcn_mfma_f32_16x16x32_bf16(ah[1], bh[1], acc, 0, 0, 0);
    acc = __builtin_amdgcn_mfma_f32_16x16x32_bf16(ah[0], bl[0], acc, 0, 0, 0);
    acc = __builtin_amdgcn_mfma_f32_16x16x32_bf16(ah[1], bl[1], acc, 0, 0, 0);
    acc = __builtin_amdgcn_mfma_f32_16x16x32_bf16(al[0], bh[0], acc, 0, 0, 0);
    acc = __builtin_amdgcn_mfma_f32_16x16x32_bf16(al[1], bh[1], acc, 0, 0, 0);

    const int colo = c0 + wv * 16 + mrow;
#pragma unroll
    for (int reg = 0; reg < 4; ++reg)
        h[(size_t)(r0 + quad * 4 + reg) * 256 + colo] = acc[reg];
}

// ---------------------------------------------------------------------------
// Kernel B1: attn_prep v2 — per (b,head). Shuffle-based bitonic sort + wave
// scans. Unchanged from R4; metadata now targets the ws meta region.
// ---------------------------------------------------------------------------
__global__ __launch_bounds__(256) void attn_prep(const float* __restrict__ h,
                                                 const float* __restrict__ att_src,
                                                 const float* __restrict__ att_dst,
                                                 int* __restrict__ g_sidx,
                                                 float* __restrict__ g_E1,
                                                 float* __restrict__ g_E2,
                                                 float* __restrict__ g_aZ,
                                                 float* __restrict__ g_bZ,
                                                 int* __restrict__ g_k) {
    const int bh = blockIdx.x;
    const int b = bh >> 2;
    const int head = bh & 3;
    const int t = threadIdx.x;
    const int lane = t & 63;
    const int wid = t >> 6;

    __shared__ float att_s[64], att_d[64];
    __shared__ float s_val[512];
    __shared__ int   s_idxE[512];
    __shared__ float dArr[512];
    __shared__ float z1suf[513], z2pre[513];
    __shared__ float wred[8];

    if (t < 64) att_s[t] = att_src[head * 64 + t];
    else if (t < 128) att_d[t - 64] = att_dst[head * 64 + (t - 64)];
    __syncthreads();

    for (int rr = 0; rr < 2; ++rr) {
        int j = t + rr * 256;
        const float* hrow = h + ((size_t)(b * 512 + j) * 4 + head) * 64;
        float as = 0.f, ad = 0.f;
#pragma unroll
        for (int d4 = 0; d4 < 16; ++d4) {
            float4 hv = *(const float4*)(hrow + d4 * 4);
            float4 sv = *(const float4*)(att_s + d4 * 4);
            float4 dv = *(const float4*)(att_d + d4 * 4);
            as += hv.x * sv.x + hv.y * sv.y + hv.z * sv.z + hv.w * sv.w;
            ad += hv.x * dv.x + hv.y * dv.y + hv.z * dv.z + hv.w * dv.w;
        }
        s_val[j] = as; dArr[j] = ad;
    }
    __syncthreads();

    float v0 = s_val[2 * t], v1 = s_val[2 * t + 1];
    int id0 = 2 * t, id1 = 2 * t + 1;
    for (int k = 2; k <= 512; k <<= 1) {
        for (int j = k >> 1; j >= 1; j >>= 1) {
            bool asc = ((t & (k >> 1)) == 0);
            if (j == 1) {
                bool sw = asc ? (v0 > v1) : (v0 < v1);
                if (sw) { float tv = v0; v0 = v1; v1 = tv; int ti = id0; id0 = id1; id1 = ti; }
            } else if (j <= 64) {
                int m = j >> 1;
                float w0 = __shfl_xor(v0, m, 64);
                int  wi0 = __shfl_xor(id0, m, 64);
                float w1 = __shfl_xor(v1, m, 64);
                int  wi1 = __shfl_xor(id1, m, 64);
                bool low = ((t & m) == 0);
                bool wantmin = (low == asc);
                if (wantmin ? (w0 < v0) : (w0 > v0)) { v0 = w0; id0 = wi0; }
                if (wantmin ? (w1 < v1) : (w1 > v1)) { v1 = w1; id1 = wi1; }
            } else {
                int m = j >> 1;
                s_val[2 * t] = v0; s_val[2 * t + 1] = v1;
                s_idxE[2 * t] = id0; s_idxE[2 * t + 1] = id1;
                __syncthreads();
                int tp = t ^ m;
                float w0 = s_val[2 * tp], w1 = s_val[2 * tp + 1];
                int wi0 = s_idxE[2 * tp], wi1 = s_idxE[2 * tp + 1];
                bool low = ((t & m) == 0);
                bool wantmin = (low == asc);
                if (wantmin ? (w0 < v0) : (w0 > v0)) { v0 = w0; id0 = wi0; }
                if (wantmin ? (w1 < v1) : (w1 > v1)) { v1 = w1; id1 = wi1; }
                __syncthreads();
            }
        }
    }

    s_val[2 * t] = v0; s_val[2 * t + 1] = v1;
    __syncthreads();
    const float M = s_val[511];
    float e1_0 = __expf(v0 - M), e1_1 = __expf(v1 - M);
    float e2_0 = __expf(0.2f * (v0 - M)), e2_1 = __expf(0.2f * (v1 - M));
    *(float2*)(g_E1 + bh * 512 + 2 * t) = make_float2(e1_0, e1_1);
    *(float2*)(g_E2 + bh * 512 + 2 * t) = make_float2(e2_0, e2_1);
    *(int2*)(g_sidx + bh * 512 + 2 * t) = make_int2(id0, id1);

    float S1 = e1_0 + e1_1, S2 = e2_0 + e2_1;
    float i1 = S1, i2 = S2;
    for (int off = 1; off < 64; off <<= 1) {
        float u1 = __shfl_up(i1, off, 64);
        float u2 = __shfl_up(i2, off, 64);
        if (lane >= off) { i1 += u1; i2 += u2; }
    }
    if (lane == 63) { wred[wid] = i1; wred[4 + wid] = i2; }
    __syncthreads();
    float off1 = 0.f, off2 = 0.f;
    for (int w = 0; w < wid; ++w) { off1 += wred[w]; off2 += wred[4 + w]; }
    const float T1 = wred[0] + wred[1] + wred[2] + wred[3];
    const float T2 = wred[4] + wred[5] + wred[6] + wred[7];
    float pre1 = off1 + i1 - S1;
    float pre2 = off2 + i2 - S2;
    z1suf[2 * t] = T1 - pre1;
    z1suf[2 * t + 1] = T1 - pre1 - e1_0;
    z2pre[2 * t] = pre2;
    z2pre[2 * t + 1] = pre2 + e2_0;
    if (t == 0) { z1suf[512] = 0.f; z2pre[512] = T2; }
    __syncthreads();

    for (int rr = 0; rr < 2; ++rr) {
        int i = t + rr * 256;
        float d = dArr[i];
        int lo = 0, hi = 512;
        while (lo < hi) {
            int mid = (lo + hi) >> 1;
            if (d + s_val[mid] >= 0.f) hi = mid; else lo = mid + 1;
        }
        int k = lo;
        float g = d + M;
        float G = (g >= 0.f) ? g : 0.2f * g;
        float al = __expf(g - G);
        float be = __expf(0.2f * g - G);
        float Z = al * z1suf[k] + be * z2pre[k];
        float inv = 1.0f / Z;
        g_aZ[bh * 512 + i] = al * inv;
        g_bZ[bh * 512 + i] = be * inv;
        g_k[bh * 512 + i]  = k;
    }
}

// ---------------------------------------------------------------------------
// Kernel B2 (R9 fusion): attn_agg_fin — block = (batch b, 8-channel group),
// iterates ALL 4 heads sequentially reusing one 16.5 KB LDS scan table 8x
// (suffix/E1 then prefix/E2 per head), accumulating the head-sum in regs,
// then writes x = relu(acc/4 + bias) DIRECTLY. Eliminates the 32 MB yH write
// + 32 MB yH read + finalize dispatch per layer. Grid 512 = 2 blocks/CU,
// 8 waves/CU. XCD swizzle: blockIdx = cg*64 + b (8 cg blocks of b co-XCD).
// ---------------------------------------------------------------------------
#define APW 516
__global__ __launch_bounds__(256) void attn_agg_fin(const float* __restrict__ h,
                                                    const int* __restrict__ g_sidx,
                                                    const float* __restrict__ g_E1,
                                                    const float* __restrict__ g_E2,
                                                    const float* __restrict__ g_aZ,
                                                    const float* __restrict__ g_bZ,
                                                    const int* __restrict__ g_k,
                                                    const float* __restrict__ bias,
                                                    float* __restrict__ x) {
    const int b  = blockIdx.x & 63;
    const int cg = blockIdx.x >> 6;        // 0..7
    const int c0 = cg * 8;
    const int t = threadIdx.x;

    __shared__ float A[8 * APW];           // 16.5 KB, reused 8x
    __shared__ float segs[8 * 33];
    __shared__ float tot[8];
    __shared__ int   kA[512];
    __shared__ float aZs[512], bZs[512];

    const int cl = t & 7, ibase = t >> 3;  // query/store mapping
    float acc[16];
#pragma unroll
    for (int p = 0; p < 16; ++p) acc[p] = 0.f;

#pragma unroll 1
    for (int head = 0; head < 4; ++head) {
        const int bh = b * 4 + head;
        __syncthreads();   // prev head's queries done before A/kA overwrite

        float e1r[2], e2r[2], hv[2][8];
        for (int rr = 0; rr < 2; ++rr) {
            int r = t + rr * 256;
            int j = g_sidx[bh * 512 + r];
            e1r[rr] = g_E1[bh * 512 + r];
            e2r[rr] = g_E2[bh * 512 + r];
            kA[r]  = g_k[bh * 512 + r];
            aZs[r] = g_aZ[bh * 512 + r];
            bZs[r] = g_bZ[bh * 512 + r];
            const float* hp = h + ((size_t)(b * 512 + j) * 4 + head) * 64 + c0;
            float4 u0 = *(const float4*)(hp);
            float4 u1 = *(const float4*)(hp + 4);
            hv[rr][0] = u0.x; hv[rr][1] = u0.y; hv[rr][2] = u0.z; hv[rr][3] = u0.w;
            hv[rr][4] = u1.x; hv[rr][5] = u1.y; hv[rr][6] = u1.z; hv[rr][7] = u1.w;
#pragma unroll
            for (int c = 0; c < 8; ++c) A[c * APW + r] = e1r[rr] * hv[rr][c];
        }
        __syncthreads();

        // ---- Pass A: inclusive suffix of E1*h ----
        {
            float* base = A + cl * APW + ibase * 16;    // 32 segs x 16 rows
            float v[16];
#pragma unroll
            for (int q4 = 0; q4 < 4; ++q4) {
                float4 a = *(const float4*)(base + q4 * 4);
                v[q4 * 4] = a.x; v[q4 * 4 + 1] = a.y; v[q4 * 4 + 2] = a.z; v[q4 * 4 + 3] = a.w;
            }
            float s = 0.f;
#pragma unroll
            for (int i = 0; i < 16; ++i) s += v[i];
            segs[cl * 33 + ibase] = s;
            __syncthreads();
            float suf = 0.f;
            for (int s2 = ibase + 1; s2 < 32; ++s2) suf += segs[cl * 33 + s2];
            float run = suf;
#pragma unroll
            for (int i = 15; i >= 0; --i) { run += v[i]; v[i] = run; }
#pragma unroll
            for (int q4 = 0; q4 < 4; ++q4)
                *(float4*)(base + q4 * 4) = make_float4(v[q4 * 4], v[q4 * 4 + 1],
                                                        v[q4 * 4 + 2], v[q4 * 4 + 3]);
        }
        __syncthreads();
        float pA[16];
#pragma unroll
        for (int p = 0; p < 16; ++p) {
            int i = p * 32 + ibase;
            int k = kA[i];
            float S1 = (k < 512) ? A[cl * APW + k] : 0.f;
            pA[p] = aZs[i] * S1;
        }
        __syncthreads();

        // ---- Pass B: exclusive prefix of E2*h ----
        for (int rr = 0; rr < 2; ++rr) {
            int r = t + rr * 256;
#pragma unroll
            for (int c = 0; c < 8; ++c) A[c * APW + r] = e2r[rr] * hv[rr][c];
        }
        __syncthreads();
        {
            float* base = A + cl * APW + ibase * 16;
            float v[16];
#pragma unroll
            for (int q4 = 0; q4 < 4; ++q4) {
                float4 a = *(const float4*)(base + q4 * 4);
                v[q4 * 4] = a.x; v[q4 * 4 + 1] = a.y; v[q4 * 4 + 2] = a.z; v[q4 * 4 + 3] = a.w;
            }
            float s = 0.f;
#pragma unroll
            for (int i = 0; i < 16; ++i) s += v[i];
            segs[cl * 33 + ibase] = s;
            __syncthreads();
            float pre = 0.f;
            for (int s2 = 0; s2 < ibase; ++s2) pre += segs[cl * 33 + s2];
            float run2 = pre;
#pragma unroll
            for (int i = 0; i < 16; ++i) { float tv = v[i]; v[i] = run2; run2 += tv; }
#pragma unroll
            for (int q4 = 0; q4 < 4; ++q4)
                *(float4*)(base + q4 * 4) = make_float4(v[q4 * 4], v[q4 * 4 + 1],
                                                        v[q4 * 4 + 2], v[q4 * 4 + 3]);
            if (ibase == 31) tot[cl] = run2;
        }
        __syncthreads();
#pragma unroll
        for (int p = 0; p < 16; ++p) {
            int i = p * 32 + ibase;
            int k = kA[i];
            float P2 = (k < 512) ? A[cl * APW + k] : tot[cl];
            acc[p] += pA[p] + bZs[i] * P2;
        }
    }

    // Finalize fused: x = relu(mean_heads + bias)
    const float bv = bias[c0 + cl];
#pragma unroll
    for (int p = 0; p < 16; ++p) {
        int i = p * 32 + ibase;
        x[(size_t)(b * 512 + i) * 64 + c0 + cl] = fmaxf(0.25f * acc[p] + bv, 0.f);
    }
}

// ---------------------------------------------------------------------------
// Kernel D: out[b][d] = (mean_n x[b][n][:]) . readout_w[d][:] + readout_b[d]
// ---------------------------------------------------------------------------
__global__ __launch_bounds__(256) void readout_kernel(const float* __restrict__ x,
                                                      const float* __restrict__ rw,
                                                      const float* __restrict__ rb,
                                                      float* __restrict__ out) {
    __shared__ float red[4][64];
    __shared__ float pooled[64];
    int b = blockIdx.x, t = threadIdx.x;
    int c = t & 63, q = t >> 6;
    float acc = 0.f;
    for (int n = q; n < 512; n += 4) acc += x[((size_t)b * 512 + n) * 64 + c];
    red[q][c] = acc;
    __syncthreads();
    if (t < 64) pooled[t] = (red[0][t] + red[1][t] + red[2][t] + red[3][t]) * (1.0f / 512.0f);
    __syncthreads();
    if (t < 64) {
        float a = rb[t];
        for (int cc = 0; cc < 64; ++cc) a += pooled[cc] * rw[t * 64 + cc];
        out[b * 64 + t] = a;
    }
}

extern "C" void kernel_launch(void* const* d_in, const int* in_sizes, int n_in,
                              void* d_out, int out_size, void* d_ws, size_t ws_size,
                              hipStream_t stream) {
    const float* emb       = (const float*)d_in[0];
    const float* lin_w     = (const float*)d_in[1];
    const float* att_src   = (const float*)d_in[2];
    const float* att_dst   = (const float*)d_in[3];
    const float* conv_b    = (const float*)d_in[4];
    const float* readout_w = (const float*)d_in[5];
    const float* readout_b = (const float*)d_in[6];
    float* out = (float*)d_out;

    float* ws   = (float*)d_ws;
    float* xbuf = ws;                    // 8 MB
    float* hbuf = ws + 2097152;          // 32 MB
    float* meta = ws + 10485760;         // 3 MB, past hbuf (ws >= 256 MB)

    int*   g_sidx = (int*)meta;
    float* g_E1   = meta + 131072;
    float* g_E2   = meta + 262144;
    float* g_aZ   = meta + 393216;
    float* g_bZ   = meta + 524288;
    int*   g_k    = (int*)(meta + 655360);

    for (int l = 0; l < 3; ++l) {
        const float* xin = (l == 0) ? emb : xbuf;
        lin_kernel<<<8192, 256, 0, stream>>>(xin, lin_w + (size_t)l * 16384, hbuf);
        attn_prep<<<256, 256, 0, stream>>>(hbuf, att_src + l * 256, att_dst + l * 256,
                                           g_sidx, g_E1, g_E2, g_aZ, g_bZ, g_k);
        attn_agg_fin<<<512, 256, 0, stream>>>(hbuf, g_sidx, g_E1, g_E2, g_aZ, g_bZ, g_k,
                                              conv_b + l * 64, xbuf);
    }
    readout_kernel<<<64, 256, 0, stream>>>(xbuf, readout_w, readout_b, out);
}

// Round 11
// 288.801 us; speedup vs baseline: 1.6347x; 1.0014x over previous
//
#include <hip/hip_runtime.h>
#include <math.h>

// Problem constants (fixed by reference): B=64, N=512, D=64, H=4, C=64, L=3
// Workspace layout (floats), ws >= 256 MB:
//   xbuf [0 .. 2097152)         : layer activations x (8 MB)
//   hT   [2097152 .. 10485760)  : h TRANSPOSED [head][c][b*512+n] (32 MB)
//   meta [10485760 .. 11534336) : prep metadata + s/d dots (4 MB)

using short8  = __attribute__((ext_vector_type(8))) short;
using floatx4 = __attribute__((ext_vector_type(4))) float;

__device__ inline unsigned short f2bf(float f) {
    union { float f; unsigned u; } v; v.f = f;
    unsigned u = v.u + 0x7FFFu + ((v.u >> 16) & 1u);   // round-to-nearest-even
    return (unsigned short)(u >> 16);
}
__device__ inline float bf2f(unsigned short s) {
    union { float f; unsigned u; } v; v.u = ((unsigned)s) << 16;
    return v.f;
}

// ---------------------------------------------------------------------------
// Kernel A v7 (MFMA split-bf16 + fused dots + transposed store):
//   hT[head][c][gn] = (x @ W^T), plus g_s/g_d = h . att_src/att_dst.
// Block (rt, ct=head) computes rows r0..r0+15 x all 64 channels of head ct,
// so it can emit the s/d dot products directly (shfl_xor over mrow lanes =
// column reduction; cross-wave add via tiny LDS). Transposed store: the 4
// quads of a wave fill each 64-B line of 16 consecutive n -> full coalescing.
// R10 rationale: kills prep's 32 MB h re-read and agg's 2x gather over-fetch.
// ---------------------------------------------------------------------------
__global__ __launch_bounds__(256) void lin_kernel(const float* __restrict__ x,
                                                  const float* __restrict__ W,
                                                  const float* __restrict__ att_src,
                                                  const float* __restrict__ att_dst,
                                                  float* __restrict__ hT,
                                                  float* __restrict__ g_s,
                                                  float* __restrict__ g_d) {
    __shared__ unsigned short XH[16 * 72], XL[16 * 72];
    __shared__ unsigned short WH[64 * 72], WL[64 * 72];
    __shared__ float sredS[4][16], sredD[4][16];

    const int t = threadIdx.x;
    const int ct = blockIdx.x & 3;        // head
    const int rt = blockIdx.x >> 2;
    const int r0 = rt * 16;
    const int c0 = ct * 64;

    // Stage x tile (16 rows x 64) as bf16 hi/lo
    {
        int row = t >> 4, d4 = t & 15;
        float4 v = *(const float4*)(x + (size_t)(r0 + row) * 64 + d4 * 4);
        unsigned short h0 = f2bf(v.x), h1 = f2bf(v.y), h2 = f2bf(v.z), h3 = f2bf(v.w);
        ushort4 hi = make_ushort4(h0, h1, h2, h3);
        ushort4 lo = make_ushort4(f2bf(v.x - bf2f(h0)), f2bf(v.y - bf2f(h1)),
                                  f2bf(v.z - bf2f(h2)), f2bf(v.w - bf2f(h3)));
        *(ushort4*)&XH[row * 72 + d4 * 4] = hi;
        *(ushort4*)&XL[row * 72 + d4 * 4] = lo;
    }
    // Stage W tile (head's 64 output rows x 64) as bf16 hi/lo
#pragma unroll
    for (int q = 0; q < 4; ++q) {
        int f = q * 256 + t;
        int wrow = f >> 4, d4 = f & 15;
        float4 v = *(const float4*)(W + (size_t)(c0 + wrow) * 64 + d4 * 4);
        unsigned short h0 = f2bf(v.x), h1 = f2bf(v.y), h2 = f2bf(v.z), h3 = f2bf(v.w);
        ushort4 hi = make_ushort4(h0, h1, h2, h3);
        ushort4 lo = make_ushort4(f2bf(v.x - bf2f(h0)), f2bf(v.y - bf2f(h1)),
                                  f2bf(v.z - bf2f(h2)), f2bf(v.w - bf2f(h3)));
        *(ushort4*)&WH[wrow * 72 + d4 * 4] = hi;
        *(ushort4*)&WL[wrow * 72 + d4 * 4] = lo;
    }
    __syncthreads();

    const int lane = t & 63, wv = t >> 6;
    const int mrow = lane & 15, quad = lane >> 4;

    short8 ah[2], al[2], bh[2], bl[2];
#pragma unroll
    for (int kk = 0; kk < 2; ++kk) {
        int ko = kk * 32 + quad * 8;
        ah[kk] = *(const short8*)&XH[mrow * 72 + ko];
        al[kk] = *(const short8*)&XL[mrow * 72 + ko];
        bh[kk] = *(const short8*)&WH[(wv * 16 + mrow) * 72 + ko];
        bl[kk] = *(const short8*)&WL[(wv * 16 + mrow) * 72 + ko];
    }

    floatx4 acc = {0.f, 0.f, 0.f, 0.f};
    acc = __builtin_amdgcn_mfma_f32_16x16x32_bf16(ah[0], bh[0], acc, 0, 0, 0);
    acc = __builtin_amdgcn_mfma_f32_16x16x32_bf16(ah[1], bh[1], acc, 0, 0, 0);
    acc = __builtin_amdgcn_mfma_f32_16x16x32_bf16(ah[0], bl[0], acc, 0, 0, 0);
    acc = __builtin_amdgcn_mfma_f32_16x16x32_bf16(ah[1], bl[1], acc, 0, 0, 0);
    acc = __builtin_amdgcn_mfma_f32_16x16x32_bf16(al[0], bh[0], acc, 0, 0, 0);
    acc = __builtin_amdgcn_mfma_f32_16x16x32_bf16(al[1], bh[1], acc, 0, 0, 0);

    // C layout: col = lane&15 (-> channel c), row = quad*4 + reg (-> n).
    // Transposed store: 4 consecutive n per lane = one float4.
    const int c = wv * 16 + mrow;
    *(float4*)&hT[(size_t)(ct * 64 + c) * 32768 + r0 + quad * 4] =
        make_float4(acc[0], acc[1], acc[2], acc[3]);

    // Fused s/d dots: sum over c of acc[reg]*att[c].
    float as_c = att_src[c0 + c];
    float ad_c = att_dst[c0 + c];
    float ps[4], pd[4];
#pragma unroll
    for (int reg = 0; reg < 4; ++reg) { ps[reg] = acc[reg] * as_c; pd[reg] = acc[reg] * ad_c; }
#pragma unroll
    for (int m = 1; m <= 8; m <<= 1) {
#pragma unroll
        for (int reg = 0; reg < 4; ++reg) {
            ps[reg] += __shfl_xor(ps[reg], m, 64);
            pd[reg] += __shfl_xor(pd[reg], m, 64);
        }
    }
    if (mrow < 4) {
        sredS[wv][quad * 4 + mrow] = ps[mrow];
        sredD[wv][quad * 4 + mrow] = pd[mrow];
    }
    __syncthreads();
    if (t < 16) {
        float sS = sredS[0][t] + sredS[1][t] + sredS[2][t] + sredS[3][t];
        float sD = sredD[0][t] + sredD[1][t] + sredD[2][t] + sredD[3][t];
        int gn = r0 + t;
        int bh = (gn >> 9) * 4 + ct;
        int n  = gn & 511;
        g_s[bh * 512 + n] = sS;
        g_d[bh * 512 + n] = sD;
    }
}

// ---------------------------------------------------------------------------
// Kernel B1: attn_prep v3 — per (b,head). Reads precomputed s/d (4 KB, was a
// 32 MB h re-read). Shuffle bitonic sort + wave scans, unchanged otherwise.
// ---------------------------------------------------------------------------
__global__ __launch_bounds__(256) void attn_prep(const float* __restrict__ g_s,
                                                 const float* __restrict__ g_d,
                                                 int* __restrict__ g_sidx,
                                                 float* __restrict__ g_E1,
                                                 float* __restrict__ g_E2,
                                                 float* __restrict__ g_aZ,
                                                 float* __restrict__ g_bZ,
                                                 int* __restrict__ g_k) {
    const int bh = blockIdx.x;
    const int t = threadIdx.x;
    const int lane = t & 63;
    const int wid = t >> 6;

    __shared__ float s_val[512];
    __shared__ int   s_idxE[512];
    __shared__ float z1suf[513], z2pre[513];
    __shared__ float wred[8];

    float dreg[2];
    for (int rr = 0; rr < 2; ++rr) {
        int j = t + rr * 256;
        s_val[j] = g_s[bh * 512 + j];
        dreg[rr] = g_d[bh * 512 + j];
    }
    __syncthreads();

    // Bitonic sort ascending; thread t holds positions 2t, 2t+1.
    float v0 = s_val[2 * t], v1 = s_val[2 * t + 1];
    int id0 = 2 * t, id1 = 2 * t + 1;
    for (int k = 2; k <= 512; k <<= 1) {
        for (int j = k >> 1; j >= 1; j >>= 1) {
            bool asc = ((t & (k >> 1)) == 0);
            if (j == 1) {
                bool sw = asc ? (v0 > v1) : (v0 < v1);
                if (sw) { float tv = v0; v0 = v1; v1 = tv; int ti = id0; id0 = id1; id1 = ti; }
            } else if (j <= 64) {
                int m = j >> 1;
                float w0 = __shfl_xor(v0, m, 64);
                int  wi0 = __shfl_xor(id0, m, 64);
                float w1 = __shfl_xor(v1, m, 64);
                int  wi1 = __shfl_xor(id1, m, 64);
                bool low = ((t & m) == 0);
                bool wantmin = (low == asc);
                if (wantmin ? (w0 < v0) : (w0 > v0)) { v0 = w0; id0 = wi0; }
                if (wantmin ? (w1 < v1) : (w1 > v1)) { v1 = w1; id1 = wi1; }
            } else {
                int m = j >> 1;
                s_val[2 * t] = v0; s_val[2 * t + 1] = v1;
                s_idxE[2 * t] = id0; s_idxE[2 * t + 1] = id1;
                __syncthreads();
                int tp = t ^ m;
                float w0 = s_val[2 * tp], w1 = s_val[2 * tp + 1];
                int wi0 = s_idxE[2 * tp], wi1 = s_idxE[2 * tp + 1];
                bool low = ((t & m) == 0);
                bool wantmin = (low == asc);
                if (wantmin ? (w0 < v0) : (w0 > v0)) { v0 = w0; id0 = wi0; }
                if (wantmin ? (w1 < v1) : (w1 > v1)) { v1 = w1; id1 = wi1; }
                __syncthreads();
            }
        }
    }

    s_val[2 * t] = v0; s_val[2 * t + 1] = v1;
    __syncthreads();
    const float M = s_val[511];
    float e1_0 = __expf(v0 - M), e1_1 = __expf(v1 - M);
    float e2_0 = __expf(0.2f * (v0 - M)), e2_1 = __expf(0.2f * (v1 - M));
    *(float2*)(g_E1 + bh * 512 + 2 * t) = make_float2(e1_0, e1_1);
    *(float2*)(g_E2 + bh * 512 + 2 * t) = make_float2(e2_0, e2_1);
    *(int2*)(g_sidx + bh * 512 + 2 * t) = make_int2(id0, id1);

    float S1 = e1_0 + e1_1, S2 = e2_0 + e2_1;
    float i1 = S1, i2 = S2;
    for (int off = 1; off < 64; off <<= 1) {
        float u1 = __shfl_up(i1, off, 64);
        float u2 = __shfl_up(i2, off, 64);
        if (lane >= off) { i1 += u1; i2 += u2; }
    }
    if (lane == 63) { wred[wid] = i1; wred[4 + wid] = i2; }
    __syncthreads();
    float off1 = 0.f, off2 = 0.f;
    for (int w = 0; w < wid; ++w) { off1 += wred[w]; off2 += wred[4 + w]; }
    const float T1 = wred[0] + wred[1] + wred[2] + wred[3];
    const float T2 = wred[4] + wred[5] + wred[6] + wred[7];
    float pre1 = off1 + i1 - S1;
    float pre2 = off2 + i2 - S2;
    z1suf[2 * t] = T1 - pre1;
    z1suf[2 * t + 1] = T1 - pre1 - e1_0;
    z2pre[2 * t] = pre2;
    z2pre[2 * t + 1] = pre2 + e2_0;
    if (t == 0) { z1suf[512] = 0.f; z2pre[512] = T2; }
    __syncthreads();

    for (int rr = 0; rr < 2; ++rr) {
        int i = t + rr * 256;
        float d = dreg[rr];
        int lo = 0, hi = 512;
        while (lo < hi) {
            int mid = (lo + hi) >> 1;
            if (d + s_val[mid] >= 0.f) hi = mid; else lo = mid + 1;
        }
        int k = lo;
        float g = d + M;
        float G = (g >= 0.f) ? g : 0.2f * g;
        float al = __expf(g - G);
        float be = __expf(0.2f * g - G);
        float Z = al * z1suf[k] + be * z2pre[k];
        float inv = 1.0f / Z;
        g_aZ[bh * 512 + i] = al * inv;
        g_bZ[bh * 512 + i] = be * inv;
        g_k[bh * 512 + i]  = k;
    }
}

// ---------------------------------------------------------------------------
// Kernel B2: attn_agg_fin v2 — gathers from TRANSPOSED hT: each (head,c,b)
// channel-row is a contiguous 2-KB window -> exact fetch (was ~2x over).
// Block = (b, 8-channel group); 4 heads sequential; one 16.5 KB LDS table
// reused 8x; x = relu(mean_heads + bias) written directly.
// ---------------------------------------------------------------------------
#define APW 516
__global__ __launch_bounds__(256) void attn_agg_fin(const float* __restrict__ hT,
                                                    const int* __restrict__ g_sidx,
                                                    const float* __restrict__ g_E1,
                                                    const float* __restrict__ g_E2,
                                                    const float* __restrict__ g_aZ,
                                                    const float* __restrict__ g_bZ,
                                                    const int* __restrict__ g_k,
                                                    const float* __restrict__ bias,
                                                    float* __restrict__ x) {
    const int b  = blockIdx.x & 63;
    const int cg = blockIdx.x >> 6;        // 0..7
    const int c0 = cg * 8;
    const int t = threadIdx.x;

    __shared__ float A[8 * APW];           // 16.5 KB, reused 8x
    __shared__ float segs[8 * 33];
    __shared__ float tot[8];
    __shared__ int   kA[512];
    __shared__ float aZs[512], bZs[512];

    const int cl = t & 7, ibase = t >> 3;
    float acc[16];
#pragma unroll
    for (int p = 0; p < 16; ++p) acc[p] = 0.f;

#pragma unroll 1
    for (int head = 0; head < 4; ++head) {
        const int bh = b * 4 + head;
        const float* hTb = hT + (size_t)(head * 64 + c0) * 32768 + b * 512;
        __syncthreads();   // prev head's queries done before A/kA overwrite

        float e1r[2], e2r[2], hv[2][8];
        for (int rr = 0; rr < 2; ++rr) {
            int r = t + rr * 256;
            int j = g_sidx[bh * 512 + r];
            e1r[rr] = g_E1[bh * 512 + r];
            e2r[rr] = g_E2[bh * 512 + r];
            kA[r]  = g_k[bh * 512 + r];
            aZs[r] = g_aZ[bh * 512 + r];
            bZs[r] = g_bZ[bh * 512 + r];
#pragma unroll
            for (int c = 0; c < 8; ++c) hv[rr][c] = hTb[c * 32768 + j];
#pragma unroll
            for (int c = 0; c < 8; ++c) A[c * APW + r] = e1r[rr] * hv[rr][c];
        }
        __syncthreads();

        // ---- Pass A: inclusive suffix of E1*h ----
        {
            float* base = A + cl * APW + ibase * 16;    // 32 segs x 16 rows
            float v[16];
#pragma unroll
            for (int q4 = 0; q4 < 4; ++q4) {
                float4 a = *(const float4*)(base + q4 * 4);
                v[q4 * 4] = a.x; v[q4 * 4 + 1] = a.y; v[q4 * 4 + 2] = a.z; v[q4 * 4 + 3] = a.w;
            }
            float s = 0.f;
#pragma unroll
            for (int i = 0; i < 16; ++i) s += v[i];
            segs[cl * 33 + ibase] = s;
            __syncthreads();
            float suf = 0.f;
            for (int s2 = ibase + 1; s2 < 32; ++s2) suf += segs[cl * 33 + s2];
            float run = suf;
#pragma unroll
            for (int i = 15; i >= 0; --i) { run += v[i]; v[i] = run; }
#pragma unroll
            for (int q4 = 0; q4 < 4; ++q4)
                *(float4*)(base + q4 * 4) = make_float4(v[q4 * 4], v[q4 * 4 + 1],
                                                        v[q4 * 4 + 2], v[q4 * 4 + 3]);
        }
        __syncthreads();
        float pA[16];
#pragma unroll
        for (int p = 0; p < 16; ++p) {
            int i = p * 32 + ibase;
            int k = kA[i];
            float S1 = (k < 512) ? A[cl * APW + k] : 0.f;
            pA[p] = aZs[i] * S1;
        }
        __syncthreads();

        // ---- Pass B: exclusive prefix of E2*h ----
        for (int rr = 0; rr < 2; ++rr) {
            int r = t + rr * 256;
#pragma unroll
            for (int c = 0; c < 8; ++c) A[c * APW + r] = e2r[rr] * hv[rr][c];
        }
        __syncthreads();
        {
            float* base = A + cl * APW + ibase * 16;
            float v[16];
#pragma unroll
            for (int q4 = 0; q4 < 4; ++q4) {
                float4 a = *(const float4*)(base + q4 * 4);
                v[q4 * 4] = a.x; v[q4 * 4 + 1] = a.y; v[q4 * 4 + 2] = a.z; v[q4 * 4 + 3] = a.w;
            }
            float s = 0.f;
#pragma unroll
            for (int i = 0; i < 16; ++i) s += v[i];
            segs[cl * 33 + ibase] = s;
            __syncthreads();
            float pre = 0.f;
            for (int s2 = 0; s2 < ibase; ++s2) pre += segs[cl * 33 + s2];
            float run2 = pre;
#pragma unroll
            for (int i = 0; i < 16; ++i) { float tv = v[i]; v[i] = run2; run2 += tv; }
#pragma unroll
            for (int q4 = 0; q4 < 4; ++q4)
                *(float4*)(base + q4 * 4) = make_float4(v[q4 * 4], v[q4 * 4 + 1],
                                                        v[q4 * 4 + 2], v[q4 * 4 + 3]);
            if (ibase == 31) tot[cl] = run2;
        }
        __syncthreads();
#pragma unroll
        for (int p = 0; p < 16; ++p) {
            int i = p * 32 + ibase;
            int k = kA[i];
            float P2 = (k < 512) ? A[cl * APW + k] : tot[cl];
            acc[p] += pA[p] + bZs[i] * P2;
        }
    }

    // Finalize fused: x = relu(mean_heads + bias)
    const float bv = bias[c0 + cl];
#pragma unroll
    for (int p = 0; p < 16; ++p) {
        int i = p * 32 + ibase;
        x[(size_t)(b * 512 + i) * 64 + c0 + cl] = fmaxf(0.25f * acc[p] + bv, 0.f);
    }
}

// ---------------------------------------------------------------------------
// Kernel D: out[b][d] = (mean_n x[b][n][:]) . readout_w[d][:] + readout_b[d]
// ---------------------------------------------------------------------------
__global__ __launch_bounds__(256) void readout_kernel(const float* __restrict__ x,
                                                      const float* __restrict__ rw,
                                                      const float* __restrict__ rb,
                                                      float* __restrict__ out) {
    __shared__ float red[4][64];
    __shared__ float pooled[64];
    int b = blockIdx.x, t = threadIdx.x;
    int c = t & 63, q = t >> 6;
    float acc = 0.f;
    for (int n = q; n < 512; n += 4) acc += x[((size_t)b * 512 + n) * 64 + c];
    red[q][c] = acc;
    __syncthreads();
    if (t < 64) pooled[t] = (red[0][t] + red[1][t] + red[2][t] + red[3][t]) * (1.0f / 512.0f);
    __syncthreads();
    if (t < 64) {
        float a = rb[t];
        for (int cc = 0; cc < 64; ++cc) a += pooled[cc] * rw[t * 64 + cc];
        out[b * 64 + t] = a;
    }
}

extern "C" void kernel_launch(void* const* d_in, const int* in_sizes, int n_in,
                              void* d_out, int out_size, void* d_ws, size_t ws_size,
                              hipStream_t stream) {
    const float* emb       = (const float*)d_in[0];
    const float* lin_w     = (const float*)d_in[1];
    const float* att_src   = (const float*)d_in[2];
    const float* att_dst   = (const float*)d_in[3];
    const float* conv_b    = (const float*)d_in[4];
    const float* readout_w = (const float*)d_in[5];
    const float* readout_b = (const float*)d_in[6];
    float* out = (float*)d_out;

    float* ws   = (float*)d_ws;
    float* xbuf = ws;                    // 8 MB
    float* hT   = ws + 2097152;          // 32 MB, [head][c][b*512+n]
    float* meta = ws + 10485760;         // 4 MB

    int*   g_sidx = (int*)meta;
    float* g_E1   = meta + 131072;
    float* g_E2   = meta + 262144;
    float* g_aZ   = meta + 393216;
    float* g_bZ   = meta + 524288;
    int*   g_k    = (int*)(meta + 655360);
    float* g_s    = meta + 786432;
    float* g_d    = meta + 917504;

    for (int l = 0; l < 3; ++l) {
        const float* xin = (l == 0) ? emb : xbuf;
        lin_kernel<<<8192, 256, 0, stream>>>(xin, lin_w + (size_t)l * 16384,
                                             att_src + l * 256, att_dst + l * 256,
                                             hT, g_s, g_d);
        attn_prep<<<256, 256, 0, stream>>>(g_s, g_d,
                                           g_sidx, g_E1, g_E2, g_aZ, g_bZ, g_k);
        attn_agg_fin<<<512, 256, 0, stream>>>(hT, g_sidx, g_E1, g_E2, g_aZ, g_bZ, g_k,
                                              conv_b + l * 64, xbuf);
    }
    readout_kernel<<<64, 256, 0, stream>>>(xbuf, readout_w, readout_b, out);
}